// Round 5
// baseline (1467.502 us; speedup 1.0000x reference)
//
#include <hip/hip_runtime.h>
#include <hip/hip_bf16.h>

#define B_ 32
#define L_ 256
#define W_ 32
#define DEPTH_ 4
#define TILE 16
#define HALO 18
#define RSTRIDE 20       // kern_last tile row stride in shorts
#define CSTRIDE 362      // kern_last tile channel stride in shorts
#define PSTRIDE 36       // kern_mid: shorts per (row,col) position (72B, 8B-aligned)
#define LL (L_*L_)

typedef float  floatx4 __attribute__((ext_vector_type(4)));
typedef float  floatx2 __attribute__((ext_vector_type(2)));
typedef short  shortx2 __attribute__((ext_vector_type(2)));
typedef short  shortx8 __attribute__((ext_vector_type(8)));

// ---- fast GELU: tanh form, hw exp2/rcp ----
__device__ __forceinline__ float gelu_fast(float x) {
    float x2 = x * x;
    float inner = fmaf(0.044715f * x2, x, x);
    float y = 0.7978845608028654f * inner;
    float e = __builtin_amdgcn_exp2f(2.8853900817779268f * fabsf(y));
    float r = __builtin_amdgcn_rcpf(1.0f + e);
    float t = fmaf(-2.0f, r, 1.0f);
    t = copysignf(t, x);
    return 0.5f * x * (1.0f + t);
}

// ---- packed f32x2 -> bf16x2 (RNE); a -> low short, b -> high short ----
#if __has_builtin(__builtin_amdgcn_cvt_pk_bf16_f32)
__device__ __forceinline__ unsigned pack_bf2(float a, float b) {
    auto v = __builtin_amdgcn_cvt_pk_bf16_f32(a, b);
    return __builtin_bit_cast(unsigned, v);
}
#else
__device__ __forceinline__ unsigned pack_bf2(float a, float b) {
    unsigned ua = __float_as_uint(a);
    unsigned ub = __float_as_uint(b);
    ua += 0x7fffu + ((ua >> 16) & 1u);
    ub += 0x7fffu + ((ub >> 16) & 1u);
    return (ua >> 16) | (ub & 0xffff0000u);
}
#endif
__device__ __forceinline__ unsigned short f2bf_fast(float v) {
    return (unsigned short)(pack_bf2(v, v) & 0xffffu);
}
__device__ __forceinline__ unsigned short f2bf(float v) {
    __hip_bfloat16 h = __float2bfloat16(v);
    return __builtin_bit_cast(unsigned short, h);
}
__device__ __forceinline__ float hi16(unsigned r) { return __uint_as_float(r & 0xffff0000u); }
__device__ __forceinline__ float lo16(unsigned r) { return __uint_as_float(r << 16); }
// dword (2 bf16) -> float2 {low short, high short}
__device__ __forceinline__ floatx2 bf2x2(unsigned r) { return floatx2{lo16(r), hi16(r)}; }

// window shorts e..e+7 in r0..r3; logical window = shorts e+1..e+6 (kern_last)
__device__ __forceinline__ void unpack6(unsigned r0, unsigned r1, unsigned r2, unsigned r3, float* w) {
    w[0] = hi16(r0);
    w[1] = lo16(r1); w[2] = hi16(r1);
    w[3] = lo16(r2); w[4] = hi16(r2);
    w[5] = lo16(r3);
}

__device__ __forceinline__ int swizzle_blk(int p) {
    return (p & 7) * 1024 + (p >> 3);
}

// ---------------- first layer: 1 channel -> 32 channels ----------------
__global__ __launch_bounds__(256) void kern_first(
        const float* __restrict__ x, float scale,
        const float* __restrict__ ci, const float* __restrict__ bi,
        const float* __restrict__ ai, const float* __restrict__ bias_i,
        __hip_bfloat16* __restrict__ hout) {
    __shared__ float tile[HALO*HALO];
    __shared__ float wC[W_], wB[W_], wA[W_], bs[W_];
    int blk = swizzle_blk(blockIdx.x);
    int b = blk >> 8;
    int t = blk & 255;
    int x0 = (t >> 4) * TILE;
    int y0 = (t & 15) * TILE;
    int tid = threadIdx.x;
    if (tid < W_) { wC[tid] = ci[tid]; wB[tid] = bi[tid]; wA[tid] = ai[tid]; bs[tid] = bias_i[tid]; }
    const float* xb = x + (size_t)b * LL;
    for (int idx = tid; idx < HALO*HALO; idx += 256) {
        int dy = idx / HALO, dx = idx % HALO;
        int gx = (x0 + dy - 1) & (L_ - 1);
        int gy = (y0 + dx - 1) & (L_ - 1);
        tile[idx] = scale * xb[gx * L_ + gy];
    }
    __syncthreads();
    int dx = tid & 15, dy = tid >> 4;
    const float* c0 = &tile[dy * HALO + dx];
    float ctr = c0[HALO + 1];
    float nb  = c0[1] + c0[2*HALO+1] + c0[HALO] + c0[HALO+2];
    float dg  = c0[0] + c0[2] + c0[2*HALO] + c0[2*HALO+2];
    unsigned short* outp = (unsigned short*)hout;
    size_t base = (size_t)b * W_ * LL + (size_t)(x0+dy) * L_ + (y0+dx);
    #pragma unroll
    for (int o = 0; o < W_; ++o) {
        float y = wC[o]*ctr + wB[o]*nb + wA[o]*dg + bs[o];
        outp[base + (size_t)o * LL] = f2bf_fast(gelu_fast(y));
    }
}

// ---------------- kern_last staging helper (channel-outer layout) ----------------
__device__ __forceinline__ void stage_row(unsigned short* tile_s, const unsigned short* hb,
                                          int j, int x0, int y0) {
    int i  = j & 31;
    int dy = j >> 5;
    int gx = (x0 + dy - 1) & (L_ - 1);
    const unsigned short* src = hb + (size_t)i * LL + (size_t)gx * L_;
    shortx8 m0 = *(const shortx8*)(src + y0);
    shortx8 m1 = *(const shortx8*)(src + y0 + 8);
    unsigned short lh = src[(y0 - 1) & (L_ - 1)];
    unsigned short rh = src[(y0 + 16) & (L_ - 1)];
    unsigned short* dst = tile_s + i * CSTRIDE + dy * RSTRIDE;
    shortx2* dp = (shortx2*)(dst + 2);
    const shortx2* p0 = (const shortx2*)&m0;
    const shortx2* p1 = (const shortx2*)&m1;
    dp[0] = p0[0]; dp[1] = p0[1]; dp[2] = p0[2]; dp[3] = p0[3];
    dp[4] = p1[0]; dp[5] = p1[1]; dp[6] = p1[2]; dp[7] = p1[3];
    dst[1]  = lh;
    dst[18] = rh;
}

// ---------------- middle layer: channel-inner tile, direct B-frags, no in-loop barriers ----
__global__ __launch_bounds__(256, 4) void kern_mid(
        const __hip_bfloat16* __restrict__ hin,
        const float* __restrict__ wc, const float* __restrict__ wb,
        const float* __restrict__ wa, const float* __restrict__ bias,
        __hip_bfloat16* __restrict__ hout) {
    // tile2[(row 0..17)*18 + (col-idx 0..17)][ch 0..31], PSTRIDE=36 shorts/pos = 23328 B
    __shared__ unsigned short tile2[18*18*PSTRIDE];

    const int tid = threadIdx.x;
    const int blk = swizzle_blk(blockIdx.x);
    const int b  = blk >> 8;
    const int t  = blk & 255;
    const int x0 = (t >> 4) * TILE;
    const int y0 = (t & 15) * TILE;

    const unsigned short* hb = (const unsigned short*)hin + (size_t)b * W_ * LL;

    // ---- stage: 288 jobs = (chpair cp2 0..15, row dy 0..17); transpose into channel-inner ----
    {
        int njobs = (tid < 32) ? 2 : 1;
        for (int jj = 0; jj < njobs; ++jj) {
            int j = tid + jj * 256;
            int cp2 = j & 15;
            int dy  = j >> 4;
            int ch0 = 2 * cp2;
            int gx = (x0 + dy - 1) & (L_ - 1);
            const unsigned short* src0 = hb + (size_t)ch0 * LL + (size_t)gx * L_;
            const unsigned short* src1 = src0 + LL;
            union { shortx8 s; unsigned u[4]; } a0, a1, c0, c1;
            a0.s = *(const shortx8*)(src0 + y0);
            a1.s = *(const shortx8*)(src0 + y0 + 8);
            c0.s = *(const shortx8*)(src1 + y0);
            c1.s = *(const shortx8*)(src1 + y0 + 8);
            unsigned lh0 = src0[(y0 - 1) & (L_ - 1)];
            unsigned rh0 = src0[(y0 + 16) & (L_ - 1)];
            unsigned lh1 = src1[(y0 - 1) & (L_ - 1)];
            unsigned rh1 = src1[(y0 + 16) & (L_ - 1)];
            unsigned short* dstb = tile2 + (dy * 18) * PSTRIDE + ch0;
            // col-idx 0 = halo left; col-idx 17 = halo right
            *(unsigned*)(dstb)                = lh0 | (lh1 << 16);
            *(unsigned*)(dstb + 17*PSTRIDE)   = rh0 | (rh1 << 16);
            #pragma unroll
            for (int c = 0; c < 16; ++c) {
                int idx = c >> 1;
                unsigned A = (idx < 4) ? a0.u[idx] : a1.u[idx-4];
                unsigned C = (idx < 4) ? c0.u[idx] : c1.u[idx-4];
                unsigned D;
                if ((c & 1) == 0) D = (A & 0xffffu) | (C << 16);
                else              D = (A >> 16)     | (C & 0xffff0000u);
                *(unsigned*)(dstb + (c + 1) * PSTRIDE) = D;
            }
        }
    }

    // ---- A fragments (weights single bf16) + bias ----
    const int lane = tid & 63;
    const int wv   = tid >> 6;
    const int m    = lane & 15;
    const int q    = lane >> 4;
    const float* wmat[3] = { wc, wb, wa };
    shortx8 afrag[3][2];
    #pragma unroll
    for (int f = 0; f < 3; ++f)
      #pragma unroll
      for (int h = 0; h < 2; ++h) {
        const float* row = wmat[f] + (h*16 + m) * W_ + q*8;
        shortx8 w;
        #pragma unroll
        for (int j = 0; j < 8; ++j) w[j] = (short)f2bf(row[j]);
        afrag[f][h] = w;
      }
    float bias_v[2][4];
    #pragma unroll
    for (int h = 0; h < 2; ++h)
      #pragma unroll
      for (int r = 0; r < 4; ++r)
        bias_v[h][r] = bias[h*16 + q*4 + r];

    __syncthreads();   // the ONLY barrier

    unsigned short* outp = (unsigned short*)hout;
    const size_t outbase = (size_t)b * W_ * LL;

    for (int p = 0; p < 4; ++p) {
        int rl = p*4 + wv;                       // site row 0..15
        // base pos = (tile-row rl, col-idx m)  -> neighborhood rows rl..rl+2, cols m..m+2
        const unsigned short* base = tile2 + (rl*18 + m) * PSTRIDE + q*8;
        union U8 { shortx8 s; unsigned u[4]; };
        U8 n00, n01, n02, n10, n11, n12, n20, n21, n22;
        n00.s = *(const shortx8*)(base);
        n01.s = *(const shortx8*)(base + PSTRIDE);
        n02.s = *(const shortx8*)(base + 2*PSTRIDE);
        n10.s = *(const shortx8*)(base + 18*PSTRIDE);
        n11.s = *(const shortx8*)(base + 19*PSTRIDE);
        n12.s = *(const shortx8*)(base + 20*PSTRIDE);
        n20.s = *(const shortx8*)(base + 36*PSTRIDE);
        n21.s = *(const shortx8*)(base + 37*PSTRIDE);
        n22.s = *(const shortx8*)(base + 38*PSTRIDE);

        U8 fnb, fdg;
        #pragma unroll
        for (int k = 0; k < 4; ++k) {
            floatx2 s1 = bf2x2(n01.u[k]) + bf2x2(n21.u[k]) + bf2x2(n10.u[k]) + bf2x2(n12.u[k]);
            fnb.u[k] = pack_bf2(s1.x, s1.y);
            floatx2 s2 = bf2x2(n00.u[k]) + bf2x2(n02.u[k]) + bf2x2(n20.u[k]) + bf2x2(n22.u[k]);
            fdg.u[k] = pack_bf2(s2.x, s2.y);
        }

        floatx4 acc[2] = {{0.f,0.f,0.f,0.f},{0.f,0.f,0.f,0.f}};
        #pragma unroll
        for (int h = 0; h < 2; ++h) {
            acc[h] = __builtin_amdgcn_mfma_f32_16x16x32_bf16(afrag[0][h], n11.s, acc[h], 0, 0, 0);
            acc[h] = __builtin_amdgcn_mfma_f32_16x16x32_bf16(afrag[1][h], fnb.s, acc[h], 0, 0, 0);
            acc[h] = __builtin_amdgcn_mfma_f32_16x16x32_bf16(afrag[2][h], fdg.s, acc[h], 0, 0, 0);
        }

        // epilogue: C/D col=lane&15 (site y), row=q*4+r (out channel within half)
        int gx = x0 + rl;
        int gy = y0 + m;
        unsigned short* dst = outp + outbase + (size_t)(q*4) * LL + (size_t)gx * L_ + gy;
        #pragma unroll
        for (int h = 0; h < 2; ++h)
          #pragma unroll
          for (int r = 0; r < 4; ++r) {
            float v = gelu_fast(acc[h][r] + bias_v[h][r]);
            dst[(size_t)(h*16 + r) * LL] = f2bf_fast(v);
          }
    }
}

// ---------------- last layer: 32 -> 1 channel, antisym accumulate ----------------
__global__ __launch_bounds__(256, 4) void kern_last(
        const __hip_bfloat16* __restrict__ hin,
        const float* __restrict__ co, const float* __restrict__ bo,
        const float* __restrict__ ao,
        float* __restrict__ out, int mode) {
    __shared__ unsigned short tile_s[W_ * CSTRIDE];
    const int tid = threadIdx.x;
    const int blk = swizzle_blk(blockIdx.x);
    const int b  = blk >> 8;
    const int t  = blk & 255;
    const int x0 = (t >> 4) * TILE;
    const int y0 = (t & 15) * TILE;

    const unsigned short* hb = (const unsigned short*)hin + (size_t)b * W_ * LL;
    stage_row(tile_s, hb, tid,       x0, y0);
    stage_row(tile_s, hb, tid + 256, x0, y0);
    if (tid < 64) stage_row(tile_s, hb, tid + 512, x0, y0);

    const int cp = tid & 15;
    const int sp = tid >> 4;
    const int rr = sp >> 2;
    const int qy = sp & 3;
    int i0 = 2*cp;
    float wC0 = co[i0], wC1 = co[i0+1];
    float wB0 = bo[i0], wB1 = bo[i0+1];
    float wA0 = ao[i0], wA1 = ao[i0+1];

    __syncthreads();
    const unsigned* tw = (const unsigned*)tile_s;

    for (int p = 0; p < 4; ++p) {
        int row = p*4 + rr;
        int wb0 = i0 * 181 + row * 10 + qy * 2;
        float ps[4];
        {
            float u[6], c[6], d[6];
            unpack6(tw[wb0],    tw[wb0+1],  tw[wb0+2],  tw[wb0+3],  u);
            unpack6(tw[wb0+10], tw[wb0+11], tw[wb0+12], tw[wb0+13], c);
            unpack6(tw[wb0+20], tw[wb0+21], tw[wb0+22], tw[wb0+23], d);
            #pragma unroll
            for (int j = 0; j < 4; ++j) {
                float ctr = c[j+1];
                float nb  = u[j+1] + d[j+1] + c[j] + c[j+2];
                float dg  = u[j] + u[j+2] + d[j] + d[j+2];
                ps[j] = wC0*ctr + wB0*nb + wA0*dg;
            }
        }
        {
            int wb1 = wb0 + 181;
            float u[6], c[6], d[6];
            unpack6(tw[wb1],    tw[wb1+1],  tw[wb1+2],  tw[wb1+3],  u);
            unpack6(tw[wb1+10], tw[wb1+11], tw[wb1+12], tw[wb1+13], c);
            unpack6(tw[wb1+20], tw[wb1+21], tw[wb1+22], tw[wb1+23], d);
            #pragma unroll
            for (int j = 0; j < 4; ++j) {
                float ctr = c[j+1];
                float nb  = u[j+1] + d[j+1] + c[j] + c[j+2];
                float dg  = u[j] + u[j+2] + d[j] + d[j+2];
                ps[j] += wC1*ctr + wB1*nb + wA1*dg;
            }
        }
        #pragma unroll
        for (int mask = 1; mask < 16; mask <<= 1) {
            #pragma unroll
            for (int j = 0; j < 4; ++j)
                ps[j] += __shfl_xor(ps[j], mask);
        }
        if (cp < 4) {
            int col = qy*4 + cp;
            size_t oidx = (size_t)b * LL + (size_t)(x0 + row) * L_ + (y0 + col);
            float v = 0.5f * ps[cp];
            if (mode == 0) out[oidx] = v;
            else           out[oidx] = out[oidx] - v;
        }
    }
}

extern "C" void kernel_launch(void* const* d_in, const int* in_sizes, int n_in,
                              void* d_out, int out_size, void* d_ws, size_t ws_size,
                              hipStream_t stream) {
    const float* x      = (const float*)d_in[0];
    const float* ai     = (const float*)d_in[1];
    const float* ao     = (const float*)d_in[2];
    const float* a      = (const float*)d_in[3];
    const float* bi     = (const float*)d_in[4];
    const float* bo     = (const float*)d_in[5];
    const float* b      = (const float*)d_in[6];
    const float* ci     = (const float*)d_in[7];
    const float* co     = (const float*)d_in[8];
    const float* c      = (const float*)d_in[9];
    const float* bias_i = (const float*)d_in[10];
    const float* bias   = (const float*)d_in[11];
    float* out = (float*)d_out;

    const size_t elems = (size_t)B_ * W_ * LL;
    __hip_bfloat16* hA = (__hip_bfloat16*)d_ws;
    __hip_bfloat16* hB = hA + elems;

    dim3 grid(B_ * 256), blk(256);
    for (int s = 0; s < 2; ++s) {
        float scale = s ? -1.0f : 1.0f;
        kern_first<<<grid, blk, 0, stream>>>(x, scale, ci, bi, ai, bias_i, hA);
        __hip_bfloat16* cur = hA; __hip_bfloat16* nxt = hB;
        for (int k = 0; k < DEPTH_; ++k) {
            kern_mid<<<grid, blk, 0, stream>>>(cur, c + k*W_*W_, b + k*W_*W_, a + k*W_*W_,
                                               bias + k*W_, nxt);
            __hip_bfloat16* tmp = cur; cur = nxt; nxt = tmp;
        }
        kern_last<<<grid, blk, 0, stream>>>(cur, co, bo, ao, out, s);
    }
}

// Round 6
// 1096.466 us; speedup vs baseline: 1.3384x; 1.3384x over previous
//
#include <hip/hip_runtime.h>
#include <hip/hip_bf16.h>

#define B_ 32
#define L_ 256
#define W_ 32
#define DEPTH_ 4
#define TILE 16
#define HALO 18
#define RSTRIDE 20       // kern_last tile row stride in shorts
#define CSTRIDE 362      // kern_last tile channel stride in shorts
#define PSTRIDE 40       // kern_mid: shorts per (row,col) position (80B = 5*16B -> b128-aligned)
#define LL (L_*L_)

typedef float  floatx4 __attribute__((ext_vector_type(4)));
typedef float  floatx2 __attribute__((ext_vector_type(2)));
typedef short  shortx2 __attribute__((ext_vector_type(2)));
typedef short  shortx8 __attribute__((ext_vector_type(8)));

// ---- fast GELU: tanh form, hw exp2/rcp ----
__device__ __forceinline__ float gelu_fast(float x) {
    float x2 = x * x;
    float inner = fmaf(0.044715f * x2, x, x);
    float y = 0.7978845608028654f * inner;
    float e = __builtin_amdgcn_exp2f(2.8853900817779268f * fabsf(y));
    float r = __builtin_amdgcn_rcpf(1.0f + e);
    float t = fmaf(-2.0f, r, 1.0f);
    t = copysignf(t, x);
    return 0.5f * x * (1.0f + t);
}

// ---- packed f32x2 -> bf16x2 (RNE); a -> low short, b -> high short ----
#if __has_builtin(__builtin_amdgcn_cvt_pk_bf16_f32)
__device__ __forceinline__ unsigned pack_bf2(float a, float b) {
    auto v = __builtin_amdgcn_cvt_pk_bf16_f32(a, b);
    return __builtin_bit_cast(unsigned, v);
}
#else
__device__ __forceinline__ unsigned pack_bf2(float a, float b) {
    unsigned ua = __float_as_uint(a);
    unsigned ub = __float_as_uint(b);
    ua += 0x7fffu + ((ua >> 16) & 1u);
    ub += 0x7fffu + ((ub >> 16) & 1u);
    return (ua >> 16) | (ub & 0xffff0000u);
}
#endif
__device__ __forceinline__ unsigned short f2bf_fast(float v) {
    return (unsigned short)(pack_bf2(v, v) & 0xffffu);
}
__device__ __forceinline__ unsigned short f2bf(float v) {
    __hip_bfloat16 h = __float2bfloat16(v);
    return __builtin_bit_cast(unsigned short, h);
}
__device__ __forceinline__ float hi16(unsigned r) { return __uint_as_float(r & 0xffff0000u); }
__device__ __forceinline__ float lo16(unsigned r) { return __uint_as_float(r << 16); }

// window shorts e..e+7 in r0..r3; logical window = shorts e+1..e+6 (kern_last)
__device__ __forceinline__ void unpack6(unsigned r0, unsigned r1, unsigned r2, unsigned r3, float* w) {
    w[0] = hi16(r0);
    w[1] = lo16(r1); w[2] = hi16(r1);
    w[3] = lo16(r2); w[4] = hi16(r2);
    w[5] = lo16(r3);
}

__device__ __forceinline__ int swizzle_blk(int p) {
    return (p & 7) * 1024 + (p >> 3);
}

// ---------------- first layer: 1 channel -> 32 channels ----------------
__global__ __launch_bounds__(256) void kern_first(
        const float* __restrict__ x, float scale,
        const float* __restrict__ ci, const float* __restrict__ bi,
        const float* __restrict__ ai, const float* __restrict__ bias_i,
        __hip_bfloat16* __restrict__ hout) {
    __shared__ float tile[HALO*HALO];
    __shared__ float wC[W_], wB[W_], wA[W_], bs[W_];
    int blk = swizzle_blk(blockIdx.x);
    int b = blk >> 8;
    int t = blk & 255;
    int x0 = (t >> 4) * TILE;
    int y0 = (t & 15) * TILE;
    int tid = threadIdx.x;
    if (tid < W_) { wC[tid] = ci[tid]; wB[tid] = bi[tid]; wA[tid] = ai[tid]; bs[tid] = bias_i[tid]; }
    const float* xb = x + (size_t)b * LL;
    for (int idx = tid; idx < HALO*HALO; idx += 256) {
        int dy = idx / HALO, dx = idx % HALO;
        int gx = (x0 + dy - 1) & (L_ - 1);
        int gy = (y0 + dx - 1) & (L_ - 1);
        tile[idx] = scale * xb[gx * L_ + gy];
    }
    __syncthreads();
    int dx = tid & 15, dy = tid >> 4;
    const float* c0 = &tile[dy * HALO + dx];
    float ctr = c0[HALO + 1];
    float nb  = c0[1] + c0[2*HALO+1] + c0[HALO] + c0[HALO+2];
    float dg  = c0[0] + c0[2] + c0[2*HALO] + c0[2*HALO+2];
    unsigned short* outp = (unsigned short*)hout;
    size_t base = (size_t)b * W_ * LL + (size_t)(x0+dy) * L_ + (y0+dx);
    #pragma unroll
    for (int o = 0; o < W_; ++o) {
        float y = wC[o]*ctr + wB[o]*nb + wA[o]*dg + bs[o];
        outp[base + (size_t)o * LL] = f2bf_fast(gelu_fast(y));
    }
}

// ---------------- kern_last staging helper (channel-outer layout) ----------------
__device__ __forceinline__ void stage_row(unsigned short* tile_s, const unsigned short* hb,
                                          int j, int x0, int y0) {
    int i  = j & 31;
    int dy = j >> 5;
    int gx = (x0 + dy - 1) & (L_ - 1);
    const unsigned short* src = hb + (size_t)i * LL + (size_t)gx * L_;
    shortx8 m0 = *(const shortx8*)(src + y0);
    shortx8 m1 = *(const shortx8*)(src + y0 + 8);
    unsigned short lh = src[(y0 - 1) & (L_ - 1)];
    unsigned short rh = src[(y0 + 16) & (L_ - 1)];
    unsigned short* dst = tile_s + i * CSTRIDE + dy * RSTRIDE;
    shortx2* dp = (shortx2*)(dst + 2);
    const shortx2* p0 = (const shortx2*)&m0;
    const shortx2* p1 = (const shortx2*)&m1;
    dp[0] = p0[0]; dp[1] = p0[1]; dp[2] = p0[2]; dp[3] = p0[3];
    dp[4] = p1[0]; dp[5] = p1[1]; dp[6] = p1[2]; dp[7] = p1[3];
    dst[1]  = lh;
    dst[18] = rh;
}

// ---------------- middle layer: channel-inner tile, 9-tap MFMA conv ----------------
// y[o][site] = sum_tap W(tap)[o][i] * x[i][site+tap]; taps read directly from LDS.
__global__ __launch_bounds__(256, 6) void kern_mid(
        const __hip_bfloat16* __restrict__ hin,
        const float* __restrict__ wc, const float* __restrict__ wb,
        const float* __restrict__ wa, const float* __restrict__ bias,
        __hip_bfloat16* __restrict__ hout) {
    // tile2[(row 0..17)*18 + (col-idx 0..17)][ch 0..31], PSTRIDE=40 shorts/pos = 25920 B
    __shared__ unsigned short tile2[18*18*PSTRIDE];

    const int tid = threadIdx.x;
    const int blk = swizzle_blk(blockIdx.x);
    const int b  = blk >> 8;
    const int t  = blk & 255;
    const int x0 = (t >> 4) * TILE;
    const int y0 = (t & 15) * TILE;

    const unsigned short* hb = (const unsigned short*)hin + (size_t)b * W_ * LL;

    // ---- stage: 288 jobs = (chpair cp2 0..15, row dy 0..17); transpose into channel-inner ----
    {
        int njobs = (tid < 32) ? 2 : 1;
        for (int jj = 0; jj < njobs; ++jj) {
            int j = tid + jj * 256;
            int cp2 = j & 15;
            int dy  = j >> 4;
            int ch0 = 2 * cp2;
            int gx = (x0 + dy - 1) & (L_ - 1);
            const unsigned short* src0 = hb + (size_t)ch0 * LL + (size_t)gx * L_;
            const unsigned short* src1 = src0 + LL;
            union { shortx8 s; unsigned u[4]; } a0, a1, c0, c1;
            a0.s = *(const shortx8*)(src0 + y0);
            a1.s = *(const shortx8*)(src0 + y0 + 8);
            c0.s = *(const shortx8*)(src1 + y0);
            c1.s = *(const shortx8*)(src1 + y0 + 8);
            unsigned lh0 = src0[(y0 - 1) & (L_ - 1)];
            unsigned rh0 = src0[(y0 + 16) & (L_ - 1)];
            unsigned lh1 = src1[(y0 - 1) & (L_ - 1)];
            unsigned rh1 = src1[(y0 + 16) & (L_ - 1)];
            unsigned short* dstb = tile2 + (dy * 18) * PSTRIDE + ch0;
            *(unsigned*)(dstb)                = lh0 | (lh1 << 16);
            *(unsigned*)(dstb + 17*PSTRIDE)   = rh0 | (rh1 << 16);
            #pragma unroll
            for (int c = 0; c < 16; ++c) {
                int idx = c >> 1;
                unsigned A = (idx < 4) ? a0.u[idx] : a1.u[idx-4];
                unsigned C = (idx < 4) ? c0.u[idx] : c1.u[idx-4];
                unsigned D;
                if ((c & 1) == 0) D = (A & 0xffffu) | (C << 16);
                else              D = (A >> 16)     | (C & 0xffff0000u);
                *(unsigned*)(dstb + (c + 1) * PSTRIDE) = D;
            }
        }
    }

    // ---- A fragments (weights single bf16) + bias ----
    const int lane = tid & 63;
    const int wv   = tid >> 6;
    const int m    = lane & 15;
    const int q    = lane >> 4;
    const float* wmat[3] = { wc, wb, wa };
    shortx8 afrag[3][2];
    #pragma unroll
    for (int f = 0; f < 3; ++f)
      #pragma unroll
      for (int h = 0; h < 2; ++h) {
        const float* row = wmat[f] + (h*16 + m) * W_ + q*8;
        shortx8 w;
        #pragma unroll
        for (int j = 0; j < 8; ++j) w[j] = (short)f2bf(row[j]);
        afrag[f][h] = w;
      }
    float bias_v[2][4];
    #pragma unroll
    for (int h = 0; h < 2; ++h)
      #pragma unroll
      for (int r = 0; r < 4; ++r)
        bias_v[h][r] = bias[h*16 + q*4 + r];

    __syncthreads();   // the ONLY barrier

    unsigned short* outp = (unsigned short*)hout;
    const size_t outbase = (size_t)b * W_ * LL;

    for (int p = 0; p < 4; ++p) {
        int rl = p*4 + wv;                       // site row 0..15
        // position (row rl, colidx m) = up-left neighbor; site = +19 positions
        const unsigned short* base = tile2 + (rl*18 + m) * PSTRIDE + q*8;
        shortx8 n00 = *(const shortx8*)(base);
        shortx8 n01 = *(const shortx8*)(base + 1*PSTRIDE);
        shortx8 n02 = *(const shortx8*)(base + 2*PSTRIDE);
        shortx8 n10 = *(const shortx8*)(base + 18*PSTRIDE);
        shortx8 n11 = *(const shortx8*)(base + 19*PSTRIDE);
        shortx8 n12 = *(const shortx8*)(base + 20*PSTRIDE);
        shortx8 n20 = *(const shortx8*)(base + 36*PSTRIDE);
        shortx8 n21 = *(const shortx8*)(base + 37*PSTRIDE);
        shortx8 n22 = *(const shortx8*)(base + 38*PSTRIDE);

        floatx4 acc[2] = {{0.f,0.f,0.f,0.f},{0.f,0.f,0.f,0.f}};
        #pragma unroll
        for (int h = 0; h < 2; ++h) {
            // center: wc
            acc[h] = __builtin_amdgcn_mfma_f32_16x16x32_bf16(afrag[0][h], n11, acc[h], 0, 0, 0);
            // 4-neighbors: wb
            acc[h] = __builtin_amdgcn_mfma_f32_16x16x32_bf16(afrag[1][h], n01, acc[h], 0, 0, 0);
            acc[h] = __builtin_amdgcn_mfma_f32_16x16x32_bf16(afrag[1][h], n21, acc[h], 0, 0, 0);
            acc[h] = __builtin_amdgcn_mfma_f32_16x16x32_bf16(afrag[1][h], n10, acc[h], 0, 0, 0);
            acc[h] = __builtin_amdgcn_mfma_f32_16x16x32_bf16(afrag[1][h], n12, acc[h], 0, 0, 0);
            // diagonals: wa
            acc[h] = __builtin_amdgcn_mfma_f32_16x16x32_bf16(afrag[2][h], n00, acc[h], 0, 0, 0);
            acc[h] = __builtin_amdgcn_mfma_f32_16x16x32_bf16(afrag[2][h], n02, acc[h], 0, 0, 0);
            acc[h] = __builtin_amdgcn_mfma_f32_16x16x32_bf16(afrag[2][h], n20, acc[h], 0, 0, 0);
            acc[h] = __builtin_amdgcn_mfma_f32_16x16x32_bf16(afrag[2][h], n22, acc[h], 0, 0, 0);
        }

        // epilogue: C/D col=lane&15 (site y), row=q*4+r (out channel within half)
        int gx = x0 + rl;
        int gy = y0 + m;
        unsigned short* dst = outp + outbase + (size_t)(q*4) * LL + (size_t)gx * L_ + gy;
        #pragma unroll
        for (int h = 0; h < 2; ++h)
          #pragma unroll
          for (int r = 0; r < 4; ++r) {
            float v = gelu_fast(acc[h][r] + bias_v[h][r]);
            dst[(size_t)(h*16 + r) * LL] = f2bf_fast(v);
          }
    }
}

// ---------------- last layer: 32 -> 1 channel, antisym accumulate ----------------
__global__ __launch_bounds__(256, 6) void kern_last(
        const __hip_bfloat16* __restrict__ hin,
        const float* __restrict__ co, const float* __restrict__ bo,
        const float* __restrict__ ao,
        float* __restrict__ out, int mode) {
    __shared__ unsigned short tile_s[W_ * CSTRIDE];
    const int tid = threadIdx.x;
    const int blk = swizzle_blk(blockIdx.x);
    const int b  = blk >> 8;
    const int t  = blk & 255;
    const int x0 = (t >> 4) * TILE;
    const int y0 = (t & 15) * TILE;

    const unsigned short* hb = (const unsigned short*)hin + (size_t)b * W_ * LL;
    stage_row(tile_s, hb, tid,       x0, y0);
    stage_row(tile_s, hb, tid + 256, x0, y0);
    if (tid < 64) stage_row(tile_s, hb, tid + 512, x0, y0);

    const int cp = tid & 15;
    const int sp = tid >> 4;
    const int rr = sp >> 2;
    const int qy = sp & 3;
    int i0 = 2*cp;
    float wC0 = co[i0], wC1 = co[i0+1];
    float wB0 = bo[i0], wB1 = bo[i0+1];
    float wA0 = ao[i0], wA1 = ao[i0+1];

    __syncthreads();
    const unsigned* tw = (const unsigned*)tile_s;

    for (int p = 0; p < 4; ++p) {
        int row = p*4 + rr;
        int wb0 = i0 * 181 + row * 10 + qy * 2;
        float ps[4];
        {
            float u[6], c[6], d[6];
            unpack6(tw[wb0],    tw[wb0+1],  tw[wb0+2],  tw[wb0+3],  u);
            unpack6(tw[wb0+10], tw[wb0+11], tw[wb0+12], tw[wb0+13], c);
            unpack6(tw[wb0+20], tw[wb0+21], tw[wb0+22], tw[wb0+23], d);
            #pragma unroll
            for (int j = 0; j < 4; ++j) {
                float ctr = c[j+1];
                float nb  = u[j+1] + d[j+1] + c[j] + c[j+2];
                float dg  = u[j] + u[j+2] + d[j] + d[j+2];
                ps[j] = wC0*ctr + wB0*nb + wA0*dg;
            }
        }
        {
            int wb1 = wb0 + 181;
            float u[6], c[6], d[6];
            unpack6(tw[wb1],    tw[wb1+1],  tw[wb1+2],  tw[wb1+3],  u);
            unpack6(tw[wb1+10], tw[wb1+11], tw[wb1+12], tw[wb1+13], c);
            unpack6(tw[wb1+20], tw[wb1+21], tw[wb1+22], tw[wb1+23], d);
            #pragma unroll
            for (int j = 0; j < 4; ++j) {
                float ctr = c[j+1];
                float nb  = u[j+1] + d[j+1] + c[j] + c[j+2];
                float dg  = u[j] + u[j+2] + d[j] + d[j+2];
                ps[j] += wC1*ctr + wB1*nb + wA1*dg;
            }
        }
        #pragma unroll
        for (int mask = 1; mask < 16; mask <<= 1) {
            #pragma unroll
            for (int j = 0; j < 4; ++j)
                ps[j] += __shfl_xor(ps[j], mask);
        }
        if (cp < 4) {
            int col = qy*4 + cp;
            size_t oidx = (size_t)b * LL + (size_t)(x0 + row) * L_ + (y0 + col);
            float v = 0.5f * ps[cp];
            if (mode == 0) out[oidx] = v;
            else           out[oidx] = out[oidx] - v;
        }
    }
}

extern "C" void kernel_launch(void* const* d_in, const int* in_sizes, int n_in,
                              void* d_out, int out_size, void* d_ws, size_t ws_size,
                              hipStream_t stream) {
    const float* x      = (const float*)d_in[0];
    const float* ai     = (const float*)d_in[1];
    const float* ao     = (const float*)d_in[2];
    const float* a      = (const float*)d_in[3];
    const float* bi     = (const float*)d_in[4];
    const float* bo     = (const float*)d_in[5];
    const float* b      = (const float*)d_in[6];
    const float* ci     = (const float*)d_in[7];
    const float* co     = (const float*)d_in[8];
    const float* c      = (const float*)d_in[9];
    const float* bias_i = (const float*)d_in[10];
    const float* bias   = (const float*)d_in[11];
    float* out = (float*)d_out;

    const size_t elems = (size_t)B_ * W_ * LL;
    __hip_bfloat16* hA = (__hip_bfloat16*)d_ws;
    __hip_bfloat16* hB = hA + elems;

    dim3 grid(B_ * 256), blk(256);
    for (int s = 0; s < 2; ++s) {
        float scale = s ? -1.0f : 1.0f;
        kern_first<<<grid, blk, 0, stream>>>(x, scale, ci, bi, ai, bias_i, hA);
        __hip_bfloat16* cur = hA; __hip_bfloat16* nxt = hB;
        for (int k = 0; k < DEPTH_; ++k) {
            kern_mid<<<grid, blk, 0, stream>>>(cur, c + k*W_*W_, b + k*W_*W_, a + k*W_*W_,
                                               bias + k*W_, nxt);
            __hip_bfloat16* tmp = cur; cur = nxt; nxt = tmp;
        }
        kern_last<<<grid, blk, 0, stream>>>(cur, co, bo, ao, out, s);
    }
}

// Round 7
// 1082.010 us; speedup vs baseline: 1.3563x; 1.0134x over previous
//
#include <hip/hip_runtime.h>
#include <hip/hip_bf16.h>

#define B_ 32
#define L_ 256
#define W_ 32
#define DEPTH_ 4
#define TILE 16
#define HALO 18
#define RSTRIDE 20       // kern_last tile row stride in shorts
#define CSTRIDE 362      // kern_last tile channel stride in shorts
#define PSTRIDE 40       // kern_mid: shorts per (row,col) position (80B = 5*16B -> b128-aligned)
#define LL (L_*L_)

typedef float  floatx4 __attribute__((ext_vector_type(4)));
typedef float  floatx2 __attribute__((ext_vector_type(2)));
typedef short  shortx2 __attribute__((ext_vector_type(2)));
typedef short  shortx8 __attribute__((ext_vector_type(8)));

// ---- fast GELU, sigmoid form: x*sigmoid(2*0.79788456*(x+0.044715 x^3)).
// Algebraically identical to 0.5x(1+tanh(y)); 1 exp2 + 1 rcp, no sign plumbing.
__device__ __forceinline__ float gelu_fast(float x) {
    float x2 = x * x;
    float inner = fmaf(0.044715f * x2, x, x);
    // z = -2*0.7978845608*log2(e) * inner
    float e = __builtin_amdgcn_exp2f(inner * -2.3022082299446597f);
    return x * __builtin_amdgcn_rcpf(1.0f + e);
}

// ---- packed f32x2 -> bf16x2 (RNE); a -> low short, b -> high short ----
#if __has_builtin(__builtin_amdgcn_cvt_pk_bf16_f32)
__device__ __forceinline__ unsigned pack_bf2(float a, float b) {
    auto v = __builtin_amdgcn_cvt_pk_bf16_f32(a, b);
    return __builtin_bit_cast(unsigned, v);
}
#else
__device__ __forceinline__ unsigned pack_bf2(float a, float b) {
    unsigned ua = __float_as_uint(a);
    unsigned ub = __float_as_uint(b);
    ua += 0x7fffu + ((ua >> 16) & 1u);
    ub += 0x7fffu + ((ub >> 16) & 1u);
    return (ua >> 16) | (ub & 0xffff0000u);
}
#endif
__device__ __forceinline__ unsigned short f2bf_fast(float v) {
    return (unsigned short)(pack_bf2(v, v) & 0xffffu);
}
__device__ __forceinline__ float hi16(unsigned r) { return __uint_as_float(r & 0xffff0000u); }
__device__ __forceinline__ float lo16(unsigned r) { return __uint_as_float(r << 16); }

// window shorts e..e+7 in r0..r3; logical window = shorts e+1..e+6 (kern_last)
__device__ __forceinline__ void unpack6(unsigned r0, unsigned r1, unsigned r2, unsigned r3, float* w) {
    w[0] = hi16(r0);
    w[1] = lo16(r1); w[2] = hi16(r1);
    w[3] = lo16(r2); w[4] = hi16(r2);
    w[5] = lo16(r3);
}

__device__ __forceinline__ int swizzle_blk(int p) {
    return (p & 7) * 1024 + (p >> 3);
}

// ---------------- first layer: 1 channel -> 32 channels ----------------
__global__ __launch_bounds__(256) void kern_first(
        const float* __restrict__ x, float scale,
        const float* __restrict__ ci, const float* __restrict__ bi,
        const float* __restrict__ ai, const float* __restrict__ bias_i,
        __hip_bfloat16* __restrict__ hout) {
    __shared__ float tile[HALO*HALO];
    __shared__ float wC[W_], wB[W_], wA[W_], bs[W_];
    int blk = swizzle_blk(blockIdx.x);
    int b = blk >> 8;
    int t = blk & 255;
    int x0 = (t >> 4) * TILE;
    int y0 = (t & 15) * TILE;
    int tid = threadIdx.x;
    if (tid < W_) { wC[tid] = ci[tid]; wB[tid] = bi[tid]; wA[tid] = ai[tid]; bs[tid] = bias_i[tid]; }
    const float* xb = x + (size_t)b * LL;
    for (int idx = tid; idx < HALO*HALO; idx += 256) {
        int dy = idx / HALO, dx = idx % HALO;
        int gx = (x0 + dy - 1) & (L_ - 1);
        int gy = (y0 + dx - 1) & (L_ - 1);
        tile[idx] = scale * xb[gx * L_ + gy];
    }
    __syncthreads();
    int dx = tid & 15, dy = tid >> 4;
    const float* c0 = &tile[dy * HALO + dx];
    float ctr = c0[HALO + 1];
    float nb  = c0[1] + c0[2*HALO+1] + c0[HALO] + c0[HALO+2];
    float dg  = c0[0] + c0[2] + c0[2*HALO] + c0[2*HALO+2];
    unsigned short* outp = (unsigned short*)hout;
    size_t base = (size_t)b * W_ * LL + (size_t)(x0+dy) * L_ + (y0+dx);
    #pragma unroll
    for (int o = 0; o < W_; ++o) {
        float y = wC[o]*ctr + wB[o]*nb + wA[o]*dg + bs[o];
        outp[base + (size_t)o * LL] = f2bf_fast(gelu_fast(y));
    }
}

// ---------------- kern_last staging helper (channel-outer layout) ----------------
__device__ __forceinline__ void stage_row(unsigned short* tile_s, const unsigned short* hb,
                                          int j, int x0, int y0) {
    int i  = j & 31;
    int dy = j >> 5;
    int gx = (x0 + dy - 1) & (L_ - 1);
    const unsigned short* src = hb + (size_t)i * LL + (size_t)gx * L_;
    shortx8 m0 = *(const shortx8*)(src + y0);
    shortx8 m1 = *(const shortx8*)(src + y0 + 8);
    unsigned short lh = src[(y0 - 1) & (L_ - 1)];
    unsigned short rh = src[(y0 + 16) & (L_ - 1)];
    unsigned short* dst = tile_s + i * CSTRIDE + dy * RSTRIDE;
    shortx2* dp = (shortx2*)(dst + 2);
    const shortx2* p0 = (const shortx2*)&m0;
    const shortx2* p1 = (const shortx2*)&m1;
    dp[0] = p0[0]; dp[1] = p0[1]; dp[2] = p0[2]; dp[3] = p0[3];
    dp[4] = p1[0]; dp[5] = p1[1]; dp[6] = p1[2]; dp[7] = p1[3];
    dst[1]  = lh;
    dst[18] = rh;
}

// ---------------- middle layer: channel-inner tile, 9-tap MFMA conv ----------------
__global__ __launch_bounds__(256, 6) void kern_mid(
        const __hip_bfloat16* __restrict__ hin,
        const float* __restrict__ wc, const float* __restrict__ wb,
        const float* __restrict__ wa, const float* __restrict__ bias,
        __hip_bfloat16* __restrict__ hout) {
    __shared__ unsigned short tile2[18*18*PSTRIDE];   // 25920 B

    const int tid = threadIdx.x;
    const int blk = swizzle_blk(blockIdx.x);
    const int b  = blk >> 8;
    const int t  = blk & 255;
    const int x0 = (t >> 4) * TILE;
    const int y0 = (t & 15) * TILE;

    const unsigned short* hb = (const unsigned short*)hin + (size_t)b * W_ * LL;

    // ---- stage: 288 jobs = (chpair cp2 0..15, row dy 0..17); transpose into channel-inner ----
    {
        int njobs = (tid < 32) ? 2 : 1;
        for (int jj = 0; jj < njobs; ++jj) {
            int j = tid + jj * 256;
            int cp2 = j & 15;
            int dy  = j >> 4;
            int ch0 = 2 * cp2;
            int gx = (x0 + dy - 1) & (L_ - 1);
            const unsigned short* src0 = hb + (size_t)ch0 * LL + (size_t)gx * L_;
            const unsigned short* src1 = src0 + LL;
            union { shortx8 s; unsigned u[4]; } a0, a1, c0, c1;
            a0.s = *(const shortx8*)(src0 + y0);
            a1.s = *(const shortx8*)(src0 + y0 + 8);
            c0.s = *(const shortx8*)(src1 + y0);
            c1.s = *(const shortx8*)(src1 + y0 + 8);
            unsigned lh0 = src0[(y0 - 1) & (L_ - 1)];
            unsigned rh0 = src0[(y0 + 16) & (L_ - 1)];
            unsigned lh1 = src1[(y0 - 1) & (L_ - 1)];
            unsigned rh1 = src1[(y0 + 16) & (L_ - 1)];
            unsigned short* dstb = tile2 + (dy * 18) * PSTRIDE + ch0;
            *(unsigned*)(dstb)                = lh0 | (lh1 << 16);
            *(unsigned*)(dstb + 17*PSTRIDE)   = rh0 | (rh1 << 16);
            #pragma unroll
            for (int c = 0; c < 16; ++c) {
                int idx = c >> 1;
                unsigned A = (idx < 4) ? a0.u[idx] : a1.u[idx-4];
                unsigned C = (idx < 4) ? c0.u[idx] : c1.u[idx-4];
                unsigned D;
                if ((c & 1) == 0) D = (A & 0xffffu) | (C << 16);
                else              D = (A >> 16)     | (C & 0xffff0000u);
                *(unsigned*)(dstb + (c + 1) * PSTRIDE) = D;
            }
        }
    }

    // ---- A fragments (weights single bf16, packed cvt) + bias ----
    const int lane = tid & 63;
    const int wv   = tid >> 6;
    const int m    = lane & 15;
    const int q    = lane >> 4;
    const float* wmat[3] = { wc, wb, wa };
    shortx8 afrag[3][2];
    #pragma unroll
    for (int f = 0; f < 3; ++f)
      #pragma unroll
      for (int h = 0; h < 2; ++h) {
        const float* row = wmat[f] + (h*16 + m) * W_ + q*8;
        floatx4 r0 = *(const floatx4*)(row);
        floatx4 r1 = *(const floatx4*)(row + 4);
        union { shortx8 s; unsigned u[4]; } w;
        w.u[0] = pack_bf2(r0.x, r0.y);
        w.u[1] = pack_bf2(r0.z, r0.w);
        w.u[2] = pack_bf2(r1.x, r1.y);
        w.u[3] = pack_bf2(r1.z, r1.w);
        afrag[f][h] = w.s;
      }
    float bias_v[2][4];
    #pragma unroll
    for (int h = 0; h < 2; ++h)
      #pragma unroll
      for (int r = 0; r < 4; ++r)
        bias_v[h][r] = bias[h*16 + q*4 + r];

    // 32-bit per-lane plane offsets (elements) for the epilogue stores
    unsigned plane_off[2][4];
    #pragma unroll
    for (int h = 0; h < 2; ++h)
      #pragma unroll
      for (int r = 0; r < 4; ++r)
        plane_off[h][r] = (unsigned)(q*4 + h*16 + r) * (unsigned)LL;

    __syncthreads();   // the ONLY barrier

    unsigned short* outb = (unsigned short*)hout + (size_t)b * W_ * LL;  // wave-uniform

    for (int p = 0; p < 4; ++p) {
        int rl = p*4 + wv;
        const unsigned short* base = tile2 + (rl*18 + m) * PSTRIDE + q*8;
        shortx8 n00 = *(const shortx8*)(base);
        shortx8 n01 = *(const shortx8*)(base + 1*PSTRIDE);
        shortx8 n02 = *(const shortx8*)(base + 2*PSTRIDE);
        shortx8 n10 = *(const shortx8*)(base + 18*PSTRIDE);
        shortx8 n11 = *(const shortx8*)(base + 19*PSTRIDE);
        shortx8 n12 = *(const shortx8*)(base + 20*PSTRIDE);
        shortx8 n20 = *(const shortx8*)(base + 36*PSTRIDE);
        shortx8 n21 = *(const shortx8*)(base + 37*PSTRIDE);
        shortx8 n22 = *(const shortx8*)(base + 38*PSTRIDE);

        floatx4 acc[2];
        #pragma unroll
        for (int h = 0; h < 2; ++h)
            acc[h] = floatx4{bias_v[h][0], bias_v[h][1], bias_v[h][2], bias_v[h][3]};
        #pragma unroll
        for (int h = 0; h < 2; ++h) {
            acc[h] = __builtin_amdgcn_mfma_f32_16x16x32_bf16(afrag[0][h], n11, acc[h], 0, 0, 0);
            acc[h] = __builtin_amdgcn_mfma_f32_16x16x32_bf16(afrag[1][h], n01, acc[h], 0, 0, 0);
            acc[h] = __builtin_amdgcn_mfma_f32_16x16x32_bf16(afrag[1][h], n21, acc[h], 0, 0, 0);
            acc[h] = __builtin_amdgcn_mfma_f32_16x16x32_bf16(afrag[1][h], n10, acc[h], 0, 0, 0);
            acc[h] = __builtin_amdgcn_mfma_f32_16x16x32_bf16(afrag[1][h], n12, acc[h], 0, 0, 0);
            acc[h] = __builtin_amdgcn_mfma_f32_16x16x32_bf16(afrag[2][h], n00, acc[h], 0, 0, 0);
            acc[h] = __builtin_amdgcn_mfma_f32_16x16x32_bf16(afrag[2][h], n02, acc[h], 0, 0, 0);
            acc[h] = __builtin_amdgcn_mfma_f32_16x16x32_bf16(afrag[2][h], n20, acc[h], 0, 0, 0);
            acc[h] = __builtin_amdgcn_mfma_f32_16x16x32_bf16(afrag[2][h], n22, acc[h], 0, 0, 0);
        }

        unsigned row_off = (unsigned)((x0 + rl) * L_ + y0 + m);
        #pragma unroll
        for (int h = 0; h < 2; ++h)
          #pragma unroll
          for (int r = 0; r < 4; ++r) {
            float v = gelu_fast(acc[h][r]);
            outb[plane_off[h][r] + row_off] = f2bf_fast(v);
          }
    }
}

// ---------------- last layer: 32 -> 1 channel, antisym accumulate ----------------
__global__ __launch_bounds__(256, 6) void kern_last(
        const __hip_bfloat16* __restrict__ hin,
        const float* __restrict__ co, const float* __restrict__ bo,
        const float* __restrict__ ao,
        float* __restrict__ out, int mode) {
    __shared__ unsigned short tile_s[W_ * CSTRIDE];
    const int tid = threadIdx.x;
    const int blk = swizzle_blk(blockIdx.x);
    const int b  = blk >> 8;
    const int t  = blk & 255;
    const int x0 = (t >> 4) * TILE;
    const int y0 = (t & 15) * TILE;

    const unsigned short* hb = (const unsigned short*)hin + (size_t)b * W_ * LL;
    stage_row(tile_s, hb, tid,       x0, y0);
    stage_row(tile_s, hb, tid + 256, x0, y0);
    if (tid < 64) stage_row(tile_s, hb, tid + 512, x0, y0);

    const int cp = tid & 15;
    const int sp = tid >> 4;
    const int rr = sp >> 2;
    const int qy = sp & 3;
    int i0 = 2*cp;
    float wC0 = co[i0], wC1 = co[i0+1];
    float wB0 = bo[i0], wB1 = bo[i0+1];
    float wA0 = ao[i0], wA1 = ao[i0+1];

    __syncthreads();
    const unsigned* tw = (const unsigned*)tile_s;

    for (int p = 0; p < 4; ++p) {
        int row = p*4 + rr;
        int wb0 = i0 * 181 + row * 10 + qy * 2;
        float ps[4];
        {
            float u[6], c[6], d[6];
            unpack6(tw[wb0],    tw[wb0+1],  tw[wb0+2],  tw[wb0+3],  u);
            unpack6(tw[wb0+10], tw[wb0+11], tw[wb0+12], tw[wb0+13], c);
            unpack6(tw[wb0+20], tw[wb0+21], tw[wb0+22], tw[wb0+23], d);
            #pragma unroll
            for (int j = 0; j < 4; ++j) {
                float ctr = c[j+1];
                float nb  = u[j+1] + d[j+1] + c[j] + c[j+2];
                float dg  = u[j] + u[j+2] + d[j] + d[j+2];
                ps[j] = wC0*ctr + wB0*nb + wA0*dg;
            }
        }
        {
            int wb1 = wb0 + 181;
            float u[6], c[6], d[6];
            unpack6(tw[wb1],    tw[wb1+1],  tw[wb1+2],  tw[wb1+3],  u);
            unpack6(tw[wb1+10], tw[wb1+11], tw[wb1+12], tw[wb1+13], c);
            unpack6(tw[wb1+20], tw[wb1+21], tw[wb1+22], tw[wb1+23], d);
            #pragma unroll
            for (int j = 0; j < 4; ++j) {
                float ctr = c[j+1];
                float nb  = u[j+1] + d[j+1] + c[j] + c[j+2];
                float dg  = u[j] + u[j+2] + d[j] + d[j+2];
                ps[j] += wC1*ctr + wB1*nb + wA1*dg;
            }
        }
        #pragma unroll
        for (int mask = 1; mask < 16; mask <<= 1) {
            #pragma unroll
            for (int j = 0; j < 4; ++j)
                ps[j] += __shfl_xor(ps[j], mask);
        }
        if (cp < 4) {
            int col = qy*4 + cp;
            size_t oidx = (size_t)b * LL + (size_t)(x0 + row) * L_ + (y0 + col);
            float v = 0.5f * ps[cp];
            if (mode == 0) out[oidx] = v;
            else           out[oidx] = out[oidx] - v;
        }
    }
}

extern "C" void kernel_launch(void* const* d_in, const int* in_sizes, int n_in,
                              void* d_out, int out_size, void* d_ws, size_t ws_size,
                              hipStream_t stream) {
    const float* x      = (const float*)d_in[0];
    const float* ai     = (const float*)d_in[1];
    const float* ao     = (const float*)d_in[2];
    const float* a      = (const float*)d_in[3];
    const float* bi     = (const float*)d_in[4];
    const float* bo     = (const float*)d_in[5];
    const float* b      = (const float*)d_in[6];
    const float* ci     = (const float*)d_in[7];
    const float* co     = (const float*)d_in[8];
    const float* c      = (const float*)d_in[9];
    const float* bias_i = (const float*)d_in[10];
    const float* bias   = (const float*)d_in[11];
    float* out = (float*)d_out;

    const size_t elems = (size_t)B_ * W_ * LL;
    __hip_bfloat16* hA = (__hip_bfloat16*)d_ws;
    __hip_bfloat16* hB = hA + elems;

    dim3 grid(B_ * 256), blk(256);
    for (int s = 0; s < 2; ++s) {
        float scale = s ? -1.0f : 1.0f;
        kern_first<<<grid, blk, 0, stream>>>(x, scale, ci, bi, ai, bias_i, hA);
        __hip_bfloat16* cur = hA; __hip_bfloat16* nxt = hB;
        for (int k = 0; k < DEPTH_; ++k) {
            kern_mid<<<grid, blk, 0, stream>>>(cur, c + k*W_*W_, b + k*W_*W_, a + k*W_*W_,
                                               bias + k*W_, nxt);
            __hip_bfloat16* tmp = cur; cur = nxt; nxt = tmp;
        }
        kern_last<<<grid, blk, 0, stream>>>(cur, co, bo, ao, out, s);
    }
}

// Round 8
// 915.258 us; speedup vs baseline: 1.6034x; 1.1822x over previous
//
#include <hip/hip_runtime.h>
#include <hip/hip_bf16.h>

#define B_ 32
#define L_ 256
#define W_ 32
#define DEPTH_ 4
#define TILE 16
#define HALO 18
#define RSTRIDE 20       // kern_last tile row stride in shorts
#define CSTRIDE 362      // kern_last tile channel stride in shorts
#define PSTRIDE 40       // shorts per (row,col) position (80B = 5*16B -> b128-aligned)
#define LL (L_*L_)

typedef float  floatx4 __attribute__((ext_vector_type(4)));
typedef short  shortx2 __attribute__((ext_vector_type(2)));
typedef short  shortx8 __attribute__((ext_vector_type(8)));
typedef unsigned uintx2 __attribute__((ext_vector_type(2)));

// ---- fast GELU, sigmoid form (algebraically = tanh form) ----
__device__ __forceinline__ float gelu_fast(float x) {
    float x2 = x * x;
    float inner = fmaf(0.044715f * x2, x, x);
    float e = __builtin_amdgcn_exp2f(inner * -2.3022082299446597f);
    return x * __builtin_amdgcn_rcpf(1.0f + e);
}

// ---- packed f32x2 -> bf16x2 (RNE); a -> low short, b -> high short ----
#if __has_builtin(__builtin_amdgcn_cvt_pk_bf16_f32)
__device__ __forceinline__ unsigned pack_bf2(float a, float b) {
    auto v = __builtin_amdgcn_cvt_pk_bf16_f32(a, b);
    return __builtin_bit_cast(unsigned, v);
}
#else
__device__ __forceinline__ unsigned pack_bf2(float a, float b) {
    unsigned ua = __float_as_uint(a);
    unsigned ub = __float_as_uint(b);
    ua += 0x7fffu + ((ua >> 16) & 1u);
    ub += 0x7fffu + ((ub >> 16) & 1u);
    return (ua >> 16) | (ub & 0xffff0000u);
}
#endif
__device__ __forceinline__ unsigned short f2bf_fast(float v) {
    return (unsigned short)(pack_bf2(v, v) & 0xffffu);
}
__device__ __forceinline__ float hi16(unsigned r) { return __uint_as_float(r & 0xffff0000u); }
__device__ __forceinline__ float lo16(unsigned r) { return __uint_as_float(r << 16); }

__device__ __forceinline__ void unpack6(unsigned r0, unsigned r1, unsigned r2, unsigned r3, float* w) {
    w[0] = hi16(r0);
    w[1] = lo16(r1); w[2] = hi16(r1);
    w[3] = lo16(r2); w[4] = hi16(r2);
    w[5] = lo16(r3);
}

__device__ __forceinline__ int swizzle_blk(int p) {
    return (p & 7) * 1024 + (p >> 3);
}

// ---------------- first layer: 1 channel -> 32 channels ----------------
__global__ __launch_bounds__(256) void kern_first(
        const float* __restrict__ x, float scale,
        const float* __restrict__ ci, const float* __restrict__ bi,
        const float* __restrict__ ai, const float* __restrict__ bias_i,
        __hip_bfloat16* __restrict__ hout) {
    __shared__ float tile[HALO*HALO];
    __shared__ float wC[W_], wB[W_], wA[W_], bs[W_];
    int blk = swizzle_blk(blockIdx.x);
    int b = blk >> 8;
    int t = blk & 255;
    int x0 = (t >> 4) * TILE;
    int y0 = (t & 15) * TILE;
    int tid = threadIdx.x;
    if (tid < W_) { wC[tid] = ci[tid]; wB[tid] = bi[tid]; wA[tid] = ai[tid]; bs[tid] = bias_i[tid]; }
    const float* xb = x + (size_t)b * LL;
    for (int idx = tid; idx < HALO*HALO; idx += 256) {
        int dy = idx / HALO, dx = idx % HALO;
        int gx = (x0 + dy - 1) & (L_ - 1);
        int gy = (y0 + dx - 1) & (L_ - 1);
        tile[idx] = scale * xb[gx * L_ + gy];
    }
    __syncthreads();
    int dx = tid & 15, dy = tid >> 4;
    const float* c0 = &tile[dy * HALO + dx];
    float ctr = c0[HALO + 1];
    float nb  = c0[1] + c0[2*HALO+1] + c0[HALO] + c0[HALO+2];
    float dg  = c0[0] + c0[2] + c0[2*HALO] + c0[2*HALO+2];
    unsigned short* outp = (unsigned short*)hout;
    size_t base = (size_t)b * W_ * LL + (size_t)(x0+dy) * L_ + (y0+dx);
    #pragma unroll
    for (int o = 0; o < W_; ++o) {
        float y = wC[o]*ctr + wB[o]*nb + wA[o]*dg + bs[o];
        outp[base + (size_t)o * LL] = f2bf_fast(gelu_fast(y));
    }
}

// ---------------- kern_last staging helper (channel-outer layout) ----------------
__device__ __forceinline__ void stage_row(unsigned short* tile_s, const unsigned short* hb,
                                          int j, int x0, int y0) {
    int i  = j & 31;
    int dy = j >> 5;
    int gx = (x0 + dy - 1) & (L_ - 1);
    const unsigned short* src = hb + (size_t)i * LL + (size_t)gx * L_;
    shortx8 m0 = *(const shortx8*)(src + y0);
    shortx8 m1 = *(const shortx8*)(src + y0 + 8);
    unsigned short lh = src[(y0 - 1) & (L_ - 1)];
    unsigned short rh = src[(y0 + 16) & (L_ - 1)];
    unsigned short* dst = tile_s + i * CSTRIDE + dy * RSTRIDE;
    shortx2* dp = (shortx2*)(dst + 2);
    const shortx2* p0 = (const shortx2*)&m0;
    const shortx2* p1 = (const shortx2*)&m1;
    dp[0] = p0[0]; dp[1] = p0[1]; dp[2] = p0[2]; dp[3] = p0[3];
    dp[4] = p1[0]; dp[5] = p1[1]; dp[6] = p1[2]; dp[7] = p1[3];
    dst[1]  = lh;
    dst[18] = rh;
}

// ---------------- fused pair of middle layers ----------------
// Stage halo-2 tile (20x20 pos x 32ch bf16, channel-inner). Layer A computed at
// the 18x18 halo-1 sites (linearized, 21 MFMA groups), outputs held in regs,
// then written over the (dead) input region. Layer B = standard 16x16 pass.
__global__ __launch_bounds__(256, 4) void kern_mid2(
        const __hip_bfloat16* __restrict__ hin,
        const float* __restrict__ wc1, const float* __restrict__ wb1,
        const float* __restrict__ wa1, const float* __restrict__ bias1,
        const float* __restrict__ wc2, const float* __restrict__ wb2,
        const float* __restrict__ wa2, const float* __restrict__ bias2,
        __hip_bfloat16* __restrict__ hout) {
    __shared__ unsigned short tile2[20*20*PSTRIDE];   // 32000 B

    const int tid = threadIdx.x;
    const int blk = swizzle_blk(blockIdx.x);
    const int b  = blk >> 8;
    const int t  = blk & 255;
    const int x0 = (t >> 4) * TILE;
    const int y0 = (t & 15) * TILE;

    const unsigned short* hb = (const unsigned short*)hin + (size_t)b * W_ * LL;

    // ---- stage: 320 jobs = (chpair 0..15, row r 0..19). Row r covers global
    // rows x0+r-2; cols y0-2..y0+17 via 4 aligned b128 loads (y0-8..y0+23). ----
    #pragma unroll
    for (int jj = 0; jj < 2; ++jj) {
        int j = tid + jj * 256;
        if (j < 320) {
            int cp2 = j & 15;
            int r   = j >> 4;
            int ch0 = 2 * cp2;
            int gx = (x0 + r - 2) & (L_ - 1);
            const unsigned short* s0 = hb + (size_t)ch0 * LL + (size_t)gx * L_;
            const unsigned short* s1 = s0 + LL;
            int cA = (y0 - 8) & (L_ - 1);
            int cD = (y0 + 16) & (L_ - 1);
            union U { shortx8 v[4]; unsigned short sh[32]; } u0, u1;
            u0.v[0] = *(const shortx8*)(s0 + cA);
            u0.v[1] = *(const shortx8*)(s0 + y0);
            u0.v[2] = *(const shortx8*)(s0 + y0 + 8);
            u0.v[3] = *(const shortx8*)(s0 + cD);
            u1.v[0] = *(const shortx8*)(s1 + cA);
            u1.v[1] = *(const shortx8*)(s1 + y0);
            u1.v[2] = *(const shortx8*)(s1 + y0 + 8);
            u1.v[3] = *(const shortx8*)(s1 + cD);
            unsigned short* dst = tile2 + (r * 20) * PSTRIDE + ch0;
            #pragma unroll
            for (int c = 0; c < 20; ++c) {
                int idx = c + 6;          // col y0+c-2 relative to y0-8
                unsigned d = (unsigned)u0.sh[idx] | ((unsigned)u1.sh[idx] << 16);
                *(unsigned*)(dst + c * PSTRIDE) = d;
            }
        }
    }

    // ---- layer-A weight fragments + bias ----
    const int lane = tid & 63;
    const int wv   = tid >> 6;
    const int m    = lane & 15;
    const int q    = lane >> 4;
    const float* wm1[3] = { wc1, wb1, wa1 };
    shortx8 afrag1[3][2];
    #pragma unroll
    for (int f = 0; f < 3; ++f)
      #pragma unroll
      for (int h = 0; h < 2; ++h) {
        const float* row = wm1[f] + (h*16 + m) * W_ + q*8;
        floatx4 r0 = *(const floatx4*)(row);
        floatx4 r1 = *(const floatx4*)(row + 4);
        union { shortx8 s; unsigned u[4]; } w;
        w.u[0] = pack_bf2(r0.x, r0.y);
        w.u[1] = pack_bf2(r0.z, r0.w);
        w.u[2] = pack_bf2(r1.x, r1.y);
        w.u[3] = pack_bf2(r1.z, r1.w);
        afrag1[f][h] = w.s;
      }
    float b1v[2][4];
    #pragma unroll
    for (int h = 0; h < 2; ++h)
      #pragma unroll
      for (int r = 0; r < 4; ++r)
        b1v[h][r] = bias1[h*16 + q*4 + r];

    __syncthreads();

    // ---- layer A: 324 sites linearized; every wave runs 6 uniform groups ----
    unsigned dwv[6][4];
    int      waddr[6];    // short-index into tile2 (h0 write address)
    #pragma unroll
    for (int k6 = 0; k6 < 6; ++k6) {
        int g = wv + 4 * k6;           // 0..23 (>=21 fully invalid)
        int s = g * 16 + m;
        int sc = s > 323 ? 323 : s;
        int i = (sc * 3641) >> 16;     // sc / 18
        int jx = sc - i * 18;          // sc % 18
        const unsigned short* base = tile2 + (i*20 + jx) * PSTRIDE + q*8;
        shortx8 n00 = *(const shortx8*)(base);
        shortx8 n01 = *(const shortx8*)(base + 1*PSTRIDE);
        shortx8 n02 = *(const shortx8*)(base + 2*PSTRIDE);
        shortx8 n10 = *(const shortx8*)(base + 20*PSTRIDE);
        shortx8 n11 = *(const shortx8*)(base + 21*PSTRIDE);
        shortx8 n12 = *(const shortx8*)(base + 22*PSTRIDE);
        shortx8 n20 = *(const shortx8*)(base + 40*PSTRIDE);
        shortx8 n21 = *(const shortx8*)(base + 41*PSTRIDE);
        shortx8 n22 = *(const shortx8*)(base + 42*PSTRIDE);
        floatx4 acc[2];
        #pragma unroll
        for (int h = 0; h < 2; ++h)
            acc[h] = floatx4{b1v[h][0], b1v[h][1], b1v[h][2], b1v[h][3]};
        #pragma unroll
        for (int h = 0; h < 2; ++h) {
            acc[h] = __builtin_amdgcn_mfma_f32_16x16x32_bf16(afrag1[0][h], n11, acc[h], 0, 0, 0);
            acc[h] = __builtin_amdgcn_mfma_f32_16x16x32_bf16(afrag1[1][h], n01, acc[h], 0, 0, 0);
            acc[h] = __builtin_amdgcn_mfma_f32_16x16x32_bf16(afrag1[1][h], n21, acc[h], 0, 0, 0);
            acc[h] = __builtin_amdgcn_mfma_f32_16x16x32_bf16(afrag1[1][h], n10, acc[h], 0, 0, 0);
            acc[h] = __builtin_amdgcn_mfma_f32_16x16x32_bf16(afrag1[1][h], n12, acc[h], 0, 0, 0);
            acc[h] = __builtin_amdgcn_mfma_f32_16x16x32_bf16(afrag1[2][h], n00, acc[h], 0, 0, 0);
            acc[h] = __builtin_amdgcn_mfma_f32_16x16x32_bf16(afrag1[2][h], n02, acc[h], 0, 0, 0);
            acc[h] = __builtin_amdgcn_mfma_f32_16x16x32_bf16(afrag1[2][h], n20, acc[h], 0, 0, 0);
            acc[h] = __builtin_amdgcn_mfma_f32_16x16x32_bf16(afrag1[2][h], n22, acc[h], 0, 0, 0);
        }
        dwv[k6][0] = pack_bf2(gelu_fast(acc[0][0]), gelu_fast(acc[0][1]));
        dwv[k6][1] = pack_bf2(gelu_fast(acc[0][2]), gelu_fast(acc[0][3]));
        dwv[k6][2] = pack_bf2(gelu_fast(acc[1][0]), gelu_fast(acc[1][1]));
        dwv[k6][3] = pack_bf2(gelu_fast(acc[1][2]), gelu_fast(acc[1][3]));
        int wi = (s < 324) ? ((i+1)*20 + (jx+1)) : (19*20 + m);   // dump -> dead halo row 19
        waddr[k6] = wi * PSTRIDE + q*4;
    }
    __syncthreads();    // all layer-A reads done; safe to overwrite tile

    #pragma unroll
    for (int k6 = 0; k6 < 6; ++k6) {
        unsigned short* wp = tile2 + waddr[k6];
        *(uintx2*)(wp)      = uintx2{dwv[k6][0], dwv[k6][1]};   // ch q*4..q*4+3
        *(uintx2*)(wp + 16) = uintx2{dwv[k6][2], dwv[k6][3]};   // ch 16+q*4..
    }

    // ---- layer-B weight fragments + bias (built here to cut layer-A VGPR peak) ----
    const float* wm2[3] = { wc2, wb2, wa2 };
    shortx8 afrag2[3][2];
    #pragma unroll
    for (int f = 0; f < 3; ++f)
      #pragma unroll
      for (int h = 0; h < 2; ++h) {
        const float* row = wm2[f] + (h*16 + m) * W_ + q*8;
        floatx4 r0 = *(const floatx4*)(row);
        floatx4 r1 = *(const floatx4*)(row + 4);
        union { shortx8 s; unsigned u[4]; } w;
        w.u[0] = pack_bf2(r0.x, r0.y);
        w.u[1] = pack_bf2(r0.z, r0.w);
        w.u[2] = pack_bf2(r1.x, r1.y);
        w.u[3] = pack_bf2(r1.z, r1.w);
        afrag2[f][h] = w.s;
      }
    float b2v[2][4];
    #pragma unroll
    for (int h = 0; h < 2; ++h)
      #pragma unroll
      for (int r = 0; r < 4; ++r)
        b2v[h][r] = bias2[h*16 + q*4 + r];
    unsigned plane_off[2][4];
    #pragma unroll
    for (int h = 0; h < 2; ++h)
      #pragma unroll
      for (int r = 0; r < 4; ++r)
        plane_off[h][r] = (unsigned)(q*4 + h*16 + r) * (unsigned)LL;

    __syncthreads();

    unsigned short* outb = (unsigned short*)hout + (size_t)b * W_ * LL;

    // ---- layer B: 16x16 sites; intermediate grid at positions (1..18,1..18) ----
    for (int p = 0; p < 4; ++p) {
        int rl = p*4 + wv;
        const unsigned short* base = tile2 + ((rl+1)*20 + (m+1)) * PSTRIDE + q*8;
        shortx8 n00 = *(const shortx8*)(base);
        shortx8 n01 = *(const shortx8*)(base + 1*PSTRIDE);
        shortx8 n02 = *(const shortx8*)(base + 2*PSTRIDE);
        shortx8 n10 = *(const shortx8*)(base + 20*PSTRIDE);
        shortx8 n11 = *(const shortx8*)(base + 21*PSTRIDE);
        shortx8 n12 = *(const shortx8*)(base + 22*PSTRIDE);
        shortx8 n20 = *(const shortx8*)(base + 40*PSTRIDE);
        shortx8 n21 = *(const shortx8*)(base + 41*PSTRIDE);
        shortx8 n22 = *(const shortx8*)(base + 42*PSTRIDE);
        floatx4 acc[2];
        #pragma unroll
        for (int h = 0; h < 2; ++h)
            acc[h] = floatx4{b2v[h][0], b2v[h][1], b2v[h][2], b2v[h][3]};
        #pragma unroll
        for (int h = 0; h < 2; ++h) {
            acc[h] = __builtin_amdgcn_mfma_f32_16x16x32_bf16(afrag2[0][h], n11, acc[h], 0, 0, 0);
            acc[h] = __builtin_amdgcn_mfma_f32_16x16x32_bf16(afrag2[1][h], n01, acc[h], 0, 0, 0);
            acc[h] = __builtin_amdgcn_mfma_f32_16x16x32_bf16(afrag2[1][h], n21, acc[h], 0, 0, 0);
            acc[h] = __builtin_amdgcn_mfma_f32_16x16x32_bf16(afrag2[1][h], n10, acc[h], 0, 0, 0);
            acc[h] = __builtin_amdgcn_mfma_f32_16x16x32_bf16(afrag2[1][h], n12, acc[h], 0, 0, 0);
            acc[h] = __builtin_amdgcn_mfma_f32_16x16x32_bf16(afrag2[2][h], n00, acc[h], 0, 0, 0);
            acc[h] = __builtin_amdgcn_mfma_f32_16x16x32_bf16(afrag2[2][h], n02, acc[h], 0, 0, 0);
            acc[h] = __builtin_amdgcn_mfma_f32_16x16x32_bf16(afrag2[2][h], n20, acc[h], 0, 0, 0);
            acc[h] = __builtin_amdgcn_mfma_f32_16x16x32_bf16(afrag2[2][h], n22, acc[h], 0, 0, 0);
        }
        unsigned row_off = (unsigned)((x0 + rl) * L_ + y0 + m);
        #pragma unroll
        for (int h = 0; h < 2; ++h)
          #pragma unroll
          for (int r = 0; r < 4; ++r) {
            float v = gelu_fast(acc[h][r]);
            outb[plane_off[h][r] + row_off] = f2bf_fast(v);
          }
    }
}

// ---------------- last layer: 32 -> 1 channel, antisym accumulate ----------------
__global__ __launch_bounds__(256, 6) void kern_last(
        const __hip_bfloat16* __restrict__ hin,
        const float* __restrict__ co, const float* __restrict__ bo,
        const float* __restrict__ ao,
        float* __restrict__ out, int mode) {
    __shared__ unsigned short tile_s[W_ * CSTRIDE];
    const int tid = threadIdx.x;
    const int blk = swizzle_blk(blockIdx.x);
    const int b  = blk >> 8;
    const int t  = blk & 255;
    const int x0 = (t >> 4) * TILE;
    const int y0 = (t & 15) * TILE;

    const unsigned short* hb = (const unsigned short*)hin + (size_t)b * W_ * LL;
    stage_row(tile_s, hb, tid,       x0, y0);
    stage_row(tile_s, hb, tid + 256, x0, y0);
    if (tid < 64) stage_row(tile_s, hb, tid + 512, x0, y0);

    const int cp = tid & 15;
    const int sp = tid >> 4;
    const int rr = sp >> 2;
    const int qy = sp & 3;
    int i0 = 2*cp;
    float wC0 = co[i0], wC1 = co[i0+1];
    float wB0 = bo[i0], wB1 = bo[i0+1];
    float wA0 = ao[i0], wA1 = ao[i0+1];

    __syncthreads();
    const unsigned* tw = (const unsigned*)tile_s;

    for (int p = 0; p < 4; ++p) {
        int row = p*4 + rr;
        int wb0 = i0 * 181 + row * 10 + qy * 2;
        float ps[4];
        {
            float u[6], c[6], d[6];
            unpack6(tw[wb0],    tw[wb0+1],  tw[wb0+2],  tw[wb0+3],  u);
            unpack6(tw[wb0+10], tw[wb0+11], tw[wb0+12], tw[wb0+13], c);
            unpack6(tw[wb0+20], tw[wb0+21], tw[wb0+22], tw[wb0+23], d);
            #pragma unroll
            for (int j = 0; j < 4; ++j) {
                float ctr = c[j+1];
                float nb  = u[j+1] + d[j+1] + c[j] + c[j+2];
                float dg  = u[j] + u[j+2] + d[j] + d[j+2];
                ps[j] = wC0*ctr + wB0*nb + wA0*dg;
            }
        }
        {
            int wb1 = wb0 + 181;
            float u[6], c[6], d[6];
            unpack6(tw[wb1],    tw[wb1+1],  tw[wb1+2],  tw[wb1+3],  u);
            unpack6(tw[wb1+10], tw[wb1+11], tw[wb1+12], tw[wb1+13], c);
            unpack6(tw[wb1+20], tw[wb1+21], tw[wb1+22], tw[wb1+23], d);
            #pragma unroll
            for (int j = 0; j < 4; ++j) {
                float ctr = c[j+1];
                float nb  = u[j+1] + d[j+1] + c[j] + c[j+2];
                float dg  = u[j] + u[j+2] + d[j] + d[j+2];
                ps[j] += wC1*ctr + wB1*nb + wA1*dg;
            }
        }
        #pragma unroll
        for (int mask = 1; mask < 16; mask <<= 1) {
            #pragma unroll
            for (int j = 0; j < 4; ++j)
                ps[j] += __shfl_xor(ps[j], mask);
        }
        if (cp < 4) {
            int col = qy*4 + cp;
            size_t oidx = (size_t)b * LL + (size_t)(x0 + row) * L_ + (y0 + col);
            float v = 0.5f * ps[cp];
            if (mode == 0) out[oidx] = v;
            else           out[oidx] = out[oidx] - v;
        }
    }
}

extern "C" void kernel_launch(void* const* d_in, const int* in_sizes, int n_in,
                              void* d_out, int out_size, void* d_ws, size_t ws_size,
                              hipStream_t stream) {
    const float* x      = (const float*)d_in[0];
    const float* ai     = (const float*)d_in[1];
    const float* ao     = (const float*)d_in[2];
    const float* a      = (const float*)d_in[3];
    const float* bi     = (const float*)d_in[4];
    const float* bo     = (const float*)d_in[5];
    const float* b      = (const float*)d_in[6];
    const float* ci     = (const float*)d_in[7];
    const float* co     = (const float*)d_in[8];
    const float* c      = (const float*)d_in[9];
    const float* bias_i = (const float*)d_in[10];
    const float* bias   = (const float*)d_in[11];
    float* out = (float*)d_out;

    const size_t elems = (size_t)B_ * W_ * LL;
    __hip_bfloat16* hA = (__hip_bfloat16*)d_ws;
    __hip_bfloat16* hB = hA + elems;

    dim3 grid(B_ * 256), blk(256);
    const int WW = W_ * W_;
    for (int s = 0; s < 2; ++s) {
        float scale = s ? -1.0f : 1.0f;
        kern_first<<<grid, blk, 0, stream>>>(x, scale, ci, bi, ai, bias_i, hA);
        kern_mid2<<<grid, blk, 0, stream>>>(hA,
            c, b, a, bias,
            c + WW, b + WW, a + WW, bias + W_,
            hB);
        kern_mid2<<<grid, blk, 0, stream>>>(hB,
            c + 2*WW, b + 2*WW, a + 2*WW, bias + 2*W_,
            c + 3*WW, b + 3*WW, a + 3*WW, bias + 3*W_,
            hA);
        kern_last<<<grid, blk, 0, stream>>>(hA, co, bo, ao, out, s);
    }
}

// Round 9
// 774.437 us; speedup vs baseline: 1.8949x; 1.1818x over previous
//
#include <hip/hip_runtime.h>
#include <hip/hip_bf16.h>

#define B_ 32
#define L_ 256
#define W_ 32
#define TILE 16
#define PSTR 40          // shorts per (row,col) position: 80B = 5*16B, b128-aligned
#define LL (L_*L_)

typedef float    floatx4 __attribute__((ext_vector_type(4)));
typedef short    shortx8 __attribute__((ext_vector_type(8)));
typedef unsigned uintx2  __attribute__((ext_vector_type(2)));
typedef unsigned uintx4  __attribute__((ext_vector_type(4)));

// ---- fast GELU, sigmoid form (algebraically = tanh approx form) ----
__device__ __forceinline__ float gelu_fast(float x) {
    float x2 = x * x;
    float inner = fmaf(0.044715f * x2, x, x);
    float e = __builtin_amdgcn_exp2f(inner * -2.3022082299446597f);
    return x * __builtin_amdgcn_rcpf(1.0f + e);
}

#if __has_builtin(__builtin_amdgcn_cvt_pk_bf16_f32)
__device__ __forceinline__ unsigned pack_bf2(float a, float b) {
    auto v = __builtin_amdgcn_cvt_pk_bf16_f32(a, b);
    return __builtin_bit_cast(unsigned, v);
}
#else
__device__ __forceinline__ unsigned pack_bf2(float a, float b) {
    unsigned ua = __float_as_uint(a);
    unsigned ub = __float_as_uint(b);
    ua += 0x7fffu + ((ua >> 16) & 1u);
    ub += 0x7fffu + ((ub >> 16) & 1u);
    return (ua >> 16) | (ub & 0xffff0000u);
}
#endif

__device__ __forceinline__ int swizzle_blk(int p) {
    return (p & 7) * 1024 + (p >> 3);
}

// 9-tap dual-half MFMA conv: first index = x (row), second = y (col)
__device__ __forceinline__ void conv9(
        const shortx8& t00, const shortx8& t01, const shortx8& t02,
        const shortx8& t10, const shortx8& t11, const shortx8& t12,
        const shortx8& t20, const shortx8& t21, const shortx8& t22,
        const shortx8 af[3][2], const float bv[2][4], floatx4 acc[2]) {
    #pragma unroll
    for (int h = 0; h < 2; ++h) {
        acc[h] = floatx4{bv[h][0], bv[h][1], bv[h][2], bv[h][3]};
        acc[h] = __builtin_amdgcn_mfma_f32_16x16x32_bf16(af[0][h], t11, acc[h], 0, 0, 0);
        acc[h] = __builtin_amdgcn_mfma_f32_16x16x32_bf16(af[1][h], t01, acc[h], 0, 0, 0);
        acc[h] = __builtin_amdgcn_mfma_f32_16x16x32_bf16(af[1][h], t21, acc[h], 0, 0, 0);
        acc[h] = __builtin_amdgcn_mfma_f32_16x16x32_bf16(af[1][h], t10, acc[h], 0, 0, 0);
        acc[h] = __builtin_amdgcn_mfma_f32_16x16x32_bf16(af[1][h], t12, acc[h], 0, 0, 0);
        acc[h] = __builtin_amdgcn_mfma_f32_16x16x32_bf16(af[2][h], t00, acc[h], 0, 0, 0);
        acc[h] = __builtin_amdgcn_mfma_f32_16x16x32_bf16(af[2][h], t02, acc[h], 0, 0, 0);
        acc[h] = __builtin_amdgcn_mfma_f32_16x16x32_bf16(af[2][h], t20, acc[h], 0, 0, 0);
        acc[h] = __builtin_amdgcn_mfma_f32_16x16x32_bf16(af[2][h], t22, acc[h], 0, 0, 0);
    }
}

__device__ __forceinline__ void gelu_pack4(const floatx4 acc[2], unsigned d[4]) {
    d[0] = pack_bf2(gelu_fast(acc[0][0]), gelu_fast(acc[0][1]));
    d[1] = pack_bf2(gelu_fast(acc[0][2]), gelu_fast(acc[0][3]));
    d[2] = pack_bf2(gelu_fast(acc[1][0]), gelu_fast(acc[1][1]));
    d[3] = pack_bf2(gelu_fast(acc[1][2]), gelu_fast(acc[1][3]));
}

__device__ __forceinline__ void build_afrag(
        const float* wc, const float* wb, const float* wa, const float* bias,
        int m, int q, shortx8 af[3][2], float bv[2][4]) {
    const float* wm[3] = { wc, wb, wa };
    #pragma unroll
    for (int f = 0; f < 3; ++f)
      #pragma unroll
      for (int h = 0; h < 2; ++h) {
        const float* row = wm[f] + (h*16 + m) * W_ + q*8;
        floatx4 r0 = *(const floatx4*)(row);
        floatx4 r1 = *(const floatx4*)(row + 4);
        union { shortx8 s; unsigned u[4]; } w;
        w.u[0] = pack_bf2(r0.x, r0.y);
        w.u[1] = pack_bf2(r0.z, r0.w);
        w.u[2] = pack_bf2(r1.x, r1.y);
        w.u[3] = pack_bf2(r1.z, r1.w);
        af[f][h] = w.s;
      }
    #pragma unroll
    for (int h = 0; h < 2; ++h)
      #pragma unroll
      for (int r = 0; r < 4; ++r)
        bv[h][r] = bias[h*16 + q*4 + r];
}

// ---------------- first layer: 1 channel -> 32 channels (site-major out) ----------------
__global__ __launch_bounds__(256) void kern_first(
        const float* __restrict__ x, float scale,
        const float* __restrict__ ci, const float* __restrict__ bi,
        const float* __restrict__ ai, const float* __restrict__ bias_i,
        unsigned short* __restrict__ hout) {
    __shared__ float tile[18*18];
    __shared__ float wC[W_], wB[W_], wA[W_], bs[W_];
    int blk = swizzle_blk(blockIdx.x);
    int b = blk >> 8;
    int t = blk & 255;
    int x0 = (t >> 4) * TILE;
    int y0 = (t & 15) * TILE;
    int tid = threadIdx.x;
    if (tid < W_) { wC[tid] = ci[tid]; wB[tid] = bi[tid]; wA[tid] = ai[tid]; bs[tid] = bias_i[tid]; }
    const float* xb = x + (size_t)b * LL;
    for (int idx = tid; idx < 18*18; idx += 256) {
        int dy = idx / 18, dx = idx % 18;
        int gx = (x0 + dy - 1) & 255;
        int gy = (y0 + dx - 1) & 255;
        tile[idx] = scale * xb[gx * L_ + gy];
    }
    __syncthreads();
    int dx = tid & 15, dy = tid >> 4;
    const float* c0 = &tile[dy * 18 + dx];
    float ctr = c0[19];
    float nb  = c0[1] + c0[37] + c0[18] + c0[20];
    float dg  = c0[0] + c0[2] + c0[36] + c0[38];
    unsigned od[16];
    #pragma unroll
    for (int o = 0; o < 16; ++o) {
        float v0 = gelu_fast(wC[2*o]*ctr + wB[2*o]*nb + wA[2*o]*dg + bs[2*o]);
        float v1 = gelu_fast(wC[2*o+1]*ctr + wB[2*o+1]*nb + wA[2*o+1]*dg + bs[2*o+1]);
        od[o] = pack_bf2(v0, v1);
    }
    unsigned* dst = (unsigned*)(hout + (((((size_t)b << 8) | (unsigned)(x0+dy)) << 8 | (unsigned)(y0+dx)) << 5));
    *(uintx4*)(dst)      = uintx4{od[0],  od[1],  od[2],  od[3]};
    *(uintx4*)(dst + 4)  = uintx4{od[4],  od[5],  od[6],  od[7]};
    *(uintx4*)(dst + 8)  = uintx4{od[8],  od[9],  od[10], od[11]};
    *(uintx4*)(dst + 12) = uintx4{od[12], od[13], od[14], od[15]};
}

// ---------------- fused middle-layer pair: site-major in/out, strip-sliding taps ----
// Position (r,c) r,c in 0..19  <->  global (x0+r-2, y0+c-2), 32ch bf16 @ PSTR.
// Layer A (mid k): 18x18 sites, site (i,j) <-> global (x0+i-1, y0+j-1),
//   taps = positions (i..i+2, j..j+2), output written (shifted) to position (i,j).
// Layer B (mid k+1): 16x16 sites, taps = positions (I..I+2, J..J+2), out to global.
__global__ __launch_bounds__(256, 4) void kern_mid2(
        const unsigned short* __restrict__ hin,
        const float* __restrict__ wc1, const float* __restrict__ wb1,
        const float* __restrict__ wa1, const float* __restrict__ bias1,
        const float* __restrict__ wc2, const float* __restrict__ wb2,
        const float* __restrict__ wa2, const float* __restrict__ bias2,
        unsigned short* __restrict__ hout) {
    __shared__ unsigned short tile2[400 * PSTR];     // 32000 B

    const int tid = threadIdx.x;
    const int blk = swizzle_blk(blockIdx.x);
    const int b  = blk >> 8;
    const int t  = blk & 255;
    const int x0 = (t >> 4) * TILE;
    const int y0 = (t & 15) * TILE;

    const unsigned short* hb = hin + ((size_t)b << 21);

    // ---- stage: pure copy, 1600 granules of 16B ----
    #pragma unroll
    for (int jj = 0; jj < 7; ++jj) {
        int j = tid + jj * 256;
        if (j < 1600) {
            int qtr = j & 3;
            int pos = j >> 2;
            int r = (pos * 3277) >> 16;     // pos / 20
            int c = pos - r * 20;
            int gx = (x0 + r - 2) & 255;
            int gy = (y0 + c - 2) & 255;
            shortx8 v = *(const shortx8*)(hb + ((((unsigned)gx << 8) | (unsigned)gy) << 5) + qtr*8);
            *(shortx8*)(tile2 + pos * PSTR + qtr * 8) = v;
        }
    }

    const int lane = tid & 63;
    const int wv   = tid >> 6;
    const int m    = lane & 15;
    const int q    = lane >> 4;

    shortx8 afrag[3][2];
    float bv[2][4];
    build_afrag(wc1, wb1, wa1, bias1, m, q, afrag, bv);

    __syncthreads();

#define LDT(tr, off) (*(const shortx8*)(tile2 + (((tr)*20 + m + (off)))*PSTR + q*8))

    // ---- layer A main: wave wv -> site rows 4wv..4wv+3, cols m (0..15) ----
    const int trow0 = wv * 4;
    shortx8 W[3][3];
    #pragma unroll
    for (int i = 0; i < 3; ++i) {
        W[i][0] = LDT(trow0 + i, 0);
        W[i][1] = LDT(trow0 + i, 1);
        W[i][2] = LDT(trow0 + i, 2);
    }
    unsigned heldA[2][4];
    #pragma unroll
    for (int rr = 0; rr < 4; ++rr) {
        const int top = rr % 3, mid = (rr + 1) % 3, bot = (rr + 2) % 3;
        floatx4 acc[2];
        conv9(W[top][0], W[top][1], W[top][2],
              W[mid][0], W[mid][1], W[mid][2],
              W[bot][0], W[bot][1], W[bot][2], afrag, bv, acc);
        unsigned d[4];
        gelu_pack4(acc, d);
        if (rr < 2) {
            heldA[rr][0] = d[0]; heldA[rr][1] = d[1];
            heldA[rr][2] = d[2]; heldA[rr][3] = d[3];
        } else {
            // rows 4wv+2,4wv+3 cols 0..15: proven unread by any concurrent wave
            unsigned short* wp = tile2 + ((trow0 + rr)*20 + m)*PSTR + q*4;
            *(uintx2*)(wp)      = uintx2{d[0], d[1]};
            *(uintx2*)(wp + 16) = uintx2{d[2], d[3]};
        }
        if (rr < 3) {
            W[top][0] = LDT(trow0 + rr + 3, 0);
            W[top][1] = LDT(trow0 + rr + 3, 1);
            W[top][2] = LDT(trow0 + rr + 3, 2);
        }
    }

    // ---- layer A edges: rows 16,17 (waves 0,1) / cols 16,17 (waves 2,3) + corners (wave 2) ----
    int er0, ec0;
    if (wv == 0)      { er0 = 16; ec0 = m;  }
    else if (wv == 1) { er0 = 17; ec0 = m;  }
    else if (wv == 2) { er0 = m;  ec0 = 16; }
    else              { er0 = m;  ec0 = 17; }
    unsigned heldE[4];
    {
        shortx8 T[3][3];
        #pragma unroll
        for (int i = 0; i < 3; ++i)
          #pragma unroll
          for (int o = 0; o < 3; ++o)
            T[i][o] = *(const shortx8*)(tile2 + ((er0 + i)*20 + ec0 + o)*PSTR + q*8);
        floatx4 acc[2];
        conv9(T[0][0], T[0][1], T[0][2], T[1][0], T[1][1], T[1][2],
              T[2][0], T[2][1], T[2][2], afrag, bv, acc);
        gelu_pack4(acc, heldE);
    }
    const int heldEoff = (er0*20 + ec0)*PSTR + q*4;

    unsigned heldC[4];
    int heldCoff = 0;
    if (wv == 2) {
        int sr = 16 + ((m >> 1) & 1);
        int sc = 16 + (m & 1);
        shortx8 T[3][3];
        #pragma unroll
        for (int i = 0; i < 3; ++i)
          #pragma unroll
          for (int o = 0; o < 3; ++o)
            T[i][o] = *(const shortx8*)(tile2 + ((sr + i)*20 + sc + o)*PSTR + q*8);
        floatx4 acc[2];
        conv9(T[0][0], T[0][1], T[0][2], T[1][0], T[1][1], T[1][2],
              T[2][0], T[2][1], T[2][2], afrag, bv, acc);
        gelu_pack4(acc, heldC);
        heldCoff = (sr*20 + sc)*PSTR + q*4;
    }

    __syncthreads();   // all layer-A tap reads complete

    #pragma unroll
    for (int rr = 0; rr < 2; ++rr) {
        unsigned short* wp = tile2 + ((trow0 + rr)*20 + m)*PSTR + q*4;
        *(uintx2*)(wp)      = uintx2{heldA[rr][0], heldA[rr][1]};
        *(uintx2*)(wp + 16) = uintx2{heldA[rr][2], heldA[rr][3]};
    }
    {
        unsigned short* wp = tile2 + heldEoff;
        *(uintx2*)(wp)      = uintx2{heldE[0], heldE[1]};
        *(uintx2*)(wp + 16) = uintx2{heldE[2], heldE[3]};
    }
    if (wv == 2 && m < 4) {
        unsigned short* wp = tile2 + heldCoff;
        *(uintx2*)(wp)      = uintx2{heldC[0], heldC[1]};
        *(uintx2*)(wp + 16) = uintx2{heldC[2], heldC[3]};
    }

    build_afrag(wc2, wb2, wa2, bias2, m, q, afrag, bv);

    __syncthreads();   // mid-k+1 field complete at positions (0..17)^2

    // ---- layer B: wave wv -> site rows 4wv..4wv+3, cols m; out to global ----
    unsigned short* outb = hout + ((size_t)b << 21);
    #pragma unroll
    for (int i = 0; i < 3; ++i) {
        W[i][0] = LDT(trow0 + i, 0);
        W[i][1] = LDT(trow0 + i, 1);
        W[i][2] = LDT(trow0 + i, 2);
    }
    #pragma unroll
    for (int rr = 0; rr < 4; ++rr) {
        const int top = rr % 3, mid = (rr + 1) % 3, bot = (rr + 2) % 3;
        floatx4 acc[2];
        conv9(W[top][0], W[top][1], W[top][2],
              W[mid][0], W[mid][1], W[mid][2],
              W[bot][0], W[bot][1], W[bot][2], afrag, bv, acc);
        unsigned d[4];
        gelu_pack4(acc, d);
        unsigned short* dst = outb + ((((unsigned)(x0 + trow0 + rr) << 8) | (unsigned)(y0 + m)) << 5) + q*4;
        *(uintx2*)(dst)      = uintx2{d[0], d[1]};
        *(uintx2*)(dst + 16) = uintx2{d[2], d[3]};
        if (rr < 3) {
            W[top][0] = LDT(trow0 + rr + 3, 0);
            W[top][1] = LDT(trow0 + rr + 3, 1);
            W[top][2] = LDT(trow0 + rr + 3, 2);
        }
    }
#undef LDT
}

// ---------------- last layer: 32 -> 1 channel via row-0 MFMA, antisym ----------------
__global__ __launch_bounds__(256, 6) void kern_last(
        const unsigned short* __restrict__ hin,
        const float* __restrict__ co, const float* __restrict__ bo,
        const float* __restrict__ ao,
        float* __restrict__ out, int mode) {
    __shared__ unsigned short tile2[324 * PSTR];     // 25920 B
    const int tid = threadIdx.x;
    const int blk = swizzle_blk(blockIdx.x);
    const int b  = blk >> 8;
    const int t  = blk & 255;
    const int x0 = (t >> 4) * TILE;
    const int y0 = (t & 15) * TILE;

    const unsigned short* hb = hin + ((size_t)b << 21);
    // stage 18x18 positions (halo 1), pure copy: 1296 granules
    #pragma unroll
    for (int jj = 0; jj < 6; ++jj) {
        int j = tid + jj * 256;
        if (j < 1296) {
            int qtr = j & 3;
            int pos = j >> 2;
            int r = (pos * 3641) >> 16;     // pos / 18
            int c = pos - r * 18;
            int gx = (x0 + r - 1) & 255;
            int gy = (y0 + c - 1) & 255;
            shortx8 v = *(const shortx8*)(hb + ((((unsigned)gx << 8) | (unsigned)gy) << 5) + qtr*8);
            *(shortx8*)(tile2 + pos * PSTR + qtr * 8) = v;
        }
    }

    const int lane = tid & 63;
    const int wv   = tid >> 6;
    const int m    = lane & 15;
    const int q    = lane >> 4;

    // A-fragments: only row 0 (out-ch 0) carries weights
    const float* wm[3] = { co, bo, ao };
    shortx8 afl[3];
    float z = (m == 0) ? 1.0f : 0.0f;
    #pragma unroll
    for (int f = 0; f < 3; ++f) {
        const float* row = wm[f] + q*8;
        floatx4 r0 = *(const floatx4*)(row);
        floatx4 r1 = *(const floatx4*)(row + 4);
        union { shortx8 s; unsigned u[4]; } w;
        w.u[0] = pack_bf2(r0.x * z, r0.y * z);
        w.u[1] = pack_bf2(r0.z * z, r0.w * z);
        w.u[2] = pack_bf2(r1.x * z, r1.y * z);
        w.u[3] = pack_bf2(r1.z * z, r1.w * z);
        afl[f] = w.s;
    }

    __syncthreads();

#define LDT18(tr, off) (*(const shortx8*)(tile2 + (((tr)*18 + m + (off)))*PSTR + q*8))
    const int trow0 = wv * 4;
    shortx8 W[3][3];
    #pragma unroll
    for (int i = 0; i < 3; ++i) {
        W[i][0] = LDT18(trow0 + i, 0);
        W[i][1] = LDT18(trow0 + i, 1);
        W[i][2] = LDT18(trow0 + i, 2);
    }
    #pragma unroll
    for (int rr = 0; rr < 4; ++rr) {
        const int top = rr % 3, mid = (rr + 1) % 3, bot = (rr + 2) % 3;
        floatx4 acc = {0.f, 0.f, 0.f, 0.f};
        acc = __builtin_amdgcn_mfma_f32_16x16x32_bf16(afl[0], W[mid][1], acc, 0, 0, 0);
        acc = __builtin_amdgcn_mfma_f32_16x16x32_bf16(afl[1], W[top][1], acc, 0, 0, 0);
        acc = __builtin_amdgcn_mfma_f32_16x16x32_bf16(afl[1], W[bot][1], acc, 0, 0, 0);
        acc = __builtin_amdgcn_mfma_f32_16x16x32_bf16(afl[1], W[mid][0], acc, 0, 0, 0);
        acc = __builtin_amdgcn_mfma_f32_16x16x32_bf16(afl[1], W[mid][2], acc, 0, 0, 0);
        acc = __builtin_amdgcn_mfma_f32_16x16x32_bf16(afl[2], W[top][0], acc, 0, 0, 0);
        acc = __builtin_amdgcn_mfma_f32_16x16x32_bf16(afl[2], W[top][2], acc, 0, 0, 0);
        acc = __builtin_amdgcn_mfma_f32_16x16x32_bf16(afl[2], W[bot][0], acc, 0, 0, 0);
        acc = __builtin_amdgcn_mfma_f32_16x16x32_bf16(afl[2], W[bot][2], acc, 0, 0, 0);
        if (q == 0) {
            size_t oidx = (size_t)b * LL + (size_t)(x0 + trow0 + rr) * L_ + (y0 + m);
            float v = 0.5f * acc[0];
            if (mode == 0) out[oidx] = v;
            else           out[oidx] = out[oidx] - v;
        }
        if (rr < 3) {
            W[top][0] = LDT18(trow0 + rr + 3, 0);
            W[top][1] = LDT18(trow0 + rr + 3, 1);
            W[top][2] = LDT18(trow0 + rr + 3, 2);
        }
    }
#undef LDT18
}

extern "C" void kernel_launch(void* const* d_in, const int* in_sizes, int n_in,
                              void* d_out, int out_size, void* d_ws, size_t ws_size,
                              hipStream_t stream) {
    const float* x      = (const float*)d_in[0];
    const float* ai     = (const float*)d_in[1];
    const float* ao     = (const float*)d_in[2];
    const float* a      = (const float*)d_in[3];
    const float* bi     = (const float*)d_in[4];
    const float* bo     = (const float*)d_in[5];
    const float* b      = (const float*)d_in[6];
    const float* ci     = (const float*)d_in[7];
    const float* co     = (const float*)d_in[8];
    const float* c      = (const float*)d_in[9];
    const float* bias_i = (const float*)d_in[10];
    const float* bias   = (const float*)d_in[11];
    float* out = (float*)d_out;

    const size_t elems = (size_t)B_ * W_ * LL;
    unsigned short* hA = (unsigned short*)d_ws;
    unsigned short* hB = hA + elems;

    dim3 grid(B_ * 256), blk(256);
    const int WW = W_ * W_;
    for (int s = 0; s < 2; ++s) {
        float scale = s ? -1.0f : 1.0f;
        kern_first<<<grid, blk, 0, stream>>>(x, scale, ci, bi, ai, bias_i, hA);
        kern_mid2<<<grid, blk, 0, stream>>>(hA,
            c, b, a, bias,
            c + WW, b + WW, a + WW, bias + W_,
            hB);
        kern_mid2<<<grid, blk, 0, stream>>>(hB,
            c + 2*WW, b + 2*WW, a + 2*WW, bias + 2*W_,
            c + 3*WW, b + 3*WW, a + 3*WW, bias + 3*W_,
            hA);
        kern_last<<<grid, blk, 0, stream>>>(hA, co, bo, ao, out, s);
    }
}